// Round 2
// baseline (2081.302 us; speedup 1.0000x reference)
//
#include <hip/hip_runtime.h>
#include <stdint.h>

#define TLEN 2048
#define DDIM 2048
#define NHEAD 16
#define HDIM 128
#define BSZ 4

typedef short bf16x8 __attribute__((ext_vector_type(8)));
typedef float f32x4 __attribute__((ext_vector_type(4)));

__device__ __forceinline__ unsigned short f32_bf16(float f) {
  union { float f; unsigned int u; } v; v.f = f;
  unsigned int u = v.u;
  unsigned int r = (u + 0x7fffu + ((u >> 16) & 1u)) >> 16;
  return (unsigned short)r;
}

// async 16B global->LDS (dest = wave-uniform base + lane*16)
__device__ __forceinline__ void async_cp16(const void* g, void* l) {
  __builtin_amdgcn_global_load_lds(
      (const __attribute__((address_space(1))) unsigned int*)g,
      (__attribute__((address_space(3))) unsigned int*)l, 16, 0, 0);
}

// ---------------- weight transpose + f32->bf16 convert ----------------
__global__ __launch_bounds__(256) void transpose_bf16_kernel(
    const float* __restrict__ in, unsigned short* __restrict__ out,
    int R, int C, long in_z, long out_z) {
  __shared__ float tile[32][33];
  in += (long)blockIdx.z * in_z;
  out += (long)blockIdx.z * out_z;
  int c0 = blockIdx.x * 32, r0 = blockIdx.y * 32;
  int cr = threadIdx.x & 31, rr = threadIdx.x >> 5;
#pragma unroll
  for (int i = 0; i < 4; ++i)
    tile[rr + i * 8][cr] = in[(long)(r0 + rr + i * 8) * C + c0 + cr];
  __syncthreads();
#pragma unroll
  for (int i = 0; i < 4; ++i)
    out[(long)(c0 + rr + i * 8) * R + r0 + cr] = f32_bf16(tile[cr][rr + i * 8]);
}

// ---------------- block reduction helper (sum, sumsq) ----------------
__device__ __forceinline__ void block_reduce2(float& s, float& q) {
#pragma unroll
  for (int off = 32; off >= 1; off >>= 1) {
    s += __shfl_xor(s, off);
    q += __shfl_xor(q, off);
  }
  __shared__ float rs[4], rq[4];
  int lane = threadIdx.x & 63, wid = threadIdx.x >> 6;
  if (lane == 0) { rs[wid] = s; rq[wid] = q; }
  __syncthreads();
  s = rs[0] + rs[1] + rs[2] + rs[3];
  q = rq[0] + rq[1] + rq[2] + rq[3];
}

// ---------------- LN1: x -> bf16 normalized ----------------
__global__ __launch_bounds__(256) void ln_kernel(
    const float* __restrict__ x, const float* __restrict__ g,
    const float* __restrict__ be, unsigned short* __restrict__ hb) {
  int row = blockIdx.x, tid = threadIdx.x;
  const float* xr = x + (long)row * DDIM;
  float4 v0 = *(const float4*)(xr + tid * 4);
  float4 v1 = *(const float4*)(xr + 1024 + tid * 4);
  float s = v0.x + v0.y + v0.z + v0.w + v1.x + v1.y + v1.z + v1.w;
  float q = v0.x * v0.x + v0.y * v0.y + v0.z * v0.z + v0.w * v0.w +
            v1.x * v1.x + v1.y * v1.y + v1.z * v1.z + v1.w * v1.w;
  block_reduce2(s, q);
  float mu = s * (1.0f / DDIM);
  float var = q * (1.0f / DDIM) - mu * mu;
  float rstd = rsqrtf(var + 1e-5f);
  float4 g0 = *(const float4*)(g + tid * 4);
  float4 g1v = *(const float4*)(g + 1024 + tid * 4);
  float4 b0 = *(const float4*)(be + tid * 4);
  float4 b1v = *(const float4*)(be + 1024 + tid * 4);
  ushort4 o0, o1;
  o0.x = f32_bf16((v0.x - mu) * rstd * g0.x + b0.x);
  o0.y = f32_bf16((v0.y - mu) * rstd * g0.y + b0.y);
  o0.z = f32_bf16((v0.z - mu) * rstd * g0.z + b0.z);
  o0.w = f32_bf16((v0.w - mu) * rstd * g0.w + b0.w);
  o1.x = f32_bf16((v1.x - mu) * rstd * g1v.x + b1v.x);
  o1.y = f32_bf16((v1.y - mu) * rstd * g1v.y + b1v.y);
  o1.z = f32_bf16((v1.z - mu) * rstd * g1v.z + b1v.z);
  o1.w = f32_bf16((v1.w - mu) * rstd * g1v.w + b1v.w);
  *(ushort4*)(hb + (long)row * DDIM + tid * 4) = o0;
  *(ushort4*)(hb + (long)row * DDIM + 1024 + tid * 4) = o1;
}

// ---------------- residual + LN2 (IN PLACE on xa==d_out) ----------------
__global__ __launch_bounds__(256) void resid_ln_kernel(
    const float* __restrict__ x, float* xa,
    const float* __restrict__ g, const float* __restrict__ be,
    unsigned short* __restrict__ hb) {
  int row = blockIdx.x, tid = threadIdx.x;
  const float* xr = x + (long)row * DDIM;
  float* ar = xa + (long)row * DDIM;
  float4 v0 = *(const float4*)(xr + tid * 4);
  float4 a0 = *(const float4*)(ar + tid * 4);
  float4 v1 = *(const float4*)(xr + 1024 + tid * 4);
  float4 a1 = *(const float4*)(ar + 1024 + tid * 4);
  v0.x += a0.x; v0.y += a0.y; v0.z += a0.z; v0.w += a0.w;
  v1.x += a1.x; v1.y += a1.y; v1.z += a1.z; v1.w += a1.w;
  *(float4*)(ar + tid * 4) = v0;
  *(float4*)(ar + 1024 + tid * 4) = v1;
  float s = v0.x + v0.y + v0.z + v0.w + v1.x + v1.y + v1.z + v1.w;
  float q = v0.x * v0.x + v0.y * v0.y + v0.z * v0.z + v0.w * v0.w +
            v1.x * v1.x + v1.y * v1.y + v1.z * v1.z + v1.w * v1.w;
  block_reduce2(s, q);
  float mu = s * (1.0f / DDIM);
  float var = q * (1.0f / DDIM) - mu * mu;
  float rstd = rsqrtf(var + 1e-5f);
  float4 g0 = *(const float4*)(g + tid * 4);
  float4 g1v = *(const float4*)(g + 1024 + tid * 4);
  float4 b0 = *(const float4*)(be + tid * 4);
  float4 b1v = *(const float4*)(be + 1024 + tid * 4);
  ushort4 o0, o1;
  o0.x = f32_bf16((v0.x - mu) * rstd * g0.x + b0.x);
  o0.y = f32_bf16((v0.y - mu) * rstd * g0.y + b0.y);
  o0.z = f32_bf16((v0.z - mu) * rstd * g0.z + b0.z);
  o0.w = f32_bf16((v0.w - mu) * rstd * g0.w + b0.w);
  o1.x = f32_bf16((v1.x - mu) * rstd * g1v.x + b1v.x);
  o1.y = f32_bf16((v1.y - mu) * rstd * g1v.y + b1v.y);
  o1.z = f32_bf16((v1.z - mu) * rstd * g1v.z + b1v.z);
  o1.w = f32_bf16((v1.w - mu) * rstd * g1v.w + b1v.w);
  *(ushort4*)(hb + (long)row * DDIM + tid * 4) = o0;
  *(ushort4*)(hb + (long)row * DDIM + 1024 + tid * 4) = o1;
}

// ---------------- MFMA GEMM core v2: global_load_lds + XOR swizzle ----------------
__device__ __forceinline__ void gemm_core(const unsigned short* __restrict__ A,
                                          const unsigned short* __restrict__ Bt,
                                          int K, int m0, int n0,
                                          f32x4 acc[4][4]) {
  __shared__ unsigned short sA[128 * 64];
  __shared__ unsigned short sB[128 * 64];
  const int tid = threadIdx.x;
  const int lane = tid & 63, wid = tid >> 6;
  const int wm = (wid & 1) * 64, wn = (wid >> 1) * 64;
  const int lm = lane & 15, lq = lane >> 4;
#pragma unroll
  for (int mi = 0; mi < 4; ++mi)
#pragma unroll
    for (int ni = 0; ni < 4; ++ni)
      acc[mi][ni] = (f32x4){0.f, 0.f, 0.f, 0.f};
  const int rbase = wid * 32;
  const int ri = lane >> 3;
  const int kgl = lane & 7;
  const int nk = K >> 6;
  for (int kt = 0; kt < nk; ++kt) {
    const unsigned short* Ak = A + (long)m0 * K + (long)kt * 64;
    const unsigned short* Bk = Bt + (long)n0 * K + (long)kt * 64;
#pragma unroll
    for (int ins = 0; ins < 4; ++ins) {
      int row = rbase + ins * 8 + ri;
      int kg = kgl ^ (row & 7);
      async_cp16(Ak + (long)row * K + kg * 8, &sA[(rbase + ins * 8) * 64]);
      async_cp16(Bk + (long)row * K + kg * 8, &sB[(rbase + ins * 8) * 64]);
    }
    __syncthreads();
#pragma unroll
    for (int kc = 0; kc < 2; ++kc) {
      bf16x8 af[4], bfr[4];
#pragma unroll
      for (int mi = 0; mi < 4; ++mi) {
        int row = wm + mi * 16 + lm;
        int kg = (kc * 4 + lq) ^ (row & 7);
        af[mi] = *(const bf16x8*)(&sA[row * 64 + kg * 8]);
      }
#pragma unroll
      for (int ni = 0; ni < 4; ++ni) {
        int row = wn + ni * 16 + lm;
        int kg = (kc * 4 + lq) ^ (row & 7);
        bfr[ni] = *(const bf16x8*)(&sB[row * 64 + kg * 8]);
      }
#pragma unroll
      for (int mi = 0; mi < 4; ++mi)
#pragma unroll
        for (int ni = 0; ni < 4; ++ni)
          acc[mi][ni] = __builtin_amdgcn_mfma_f32_16x16x32_bf16(af[mi], bfr[ni], acc[mi][ni], 0, 0, 0);
    }
    __syncthreads();
  }
}

// ---------------- QKV projection GEMM (z: 0=Q,1=K,2=V-transposed) ----------------
__global__ __launch_bounds__(256) void gemm_qkv_kernel(
    const unsigned short* __restrict__ A, const unsigned short* __restrict__ WT,
    unsigned short* __restrict__ Qb, unsigned short* __restrict__ Kb,
    unsigned short* __restrict__ VTb,
    const float* __restrict__ bq, const float* __restrict__ bk,
    const float* __restrict__ bv) {
  int m0 = blockIdx.x * 128, n0 = blockIdx.y * 128;
  int z = blockIdx.z;
  const unsigned short* Bt = WT + (long)z * DDIM * DDIM;
  f32x4 acc[4][4];
  gemm_core(A, Bt, DDIM, m0, n0, acc);
  const float* bias = (z == 0) ? bq : (z == 1) ? bk : bv;
  int lane = threadIdx.x & 63, wid = threadIdx.x >> 6;
  int wm = (wid & 1) * 64, wn = (wid >> 1) * 64, lm = lane & 15, lq = lane >> 4;
  int h = n0 >> 7;
#pragma unroll
  for (int mi = 0; mi < 4; ++mi) {
    int rowb = m0 + wm + mi * 16 + lq * 4;
    int b = rowb >> 11, t0 = rowb & (TLEN - 1);
#pragma unroll
    for (int ni = 0; ni < 4; ++ni) {
      int col = n0 + wn + ni * 16 + lm;
      int e = col & (HDIM - 1);
      float bsv = bias[col];
      if (z < 2) {
        unsigned short* o = (z == 0) ? Qb : Kb;
        long base = ((long)(b * NHEAD + h) * TLEN + t0) * HDIM + e;
#pragma unroll
        for (int r = 0; r < 4; ++r)
          o[base + (long)r * HDIM] = f32_bf16(acc[mi][ni][r] + bsv);
      } else {
        long base = ((long)(b * NHEAD + h) * HDIM + e) * TLEN + t0;
        ushort4 pk;
        pk.x = f32_bf16(acc[mi][ni][0] + bsv);
        pk.y = f32_bf16(acc[mi][ni][1] + bsv);
        pk.z = f32_bf16(acc[mi][ni][2] + bsv);
        pk.w = f32_bf16(acc[mi][ni][3] + bsv);
        *(ushort4*)(VTb + base) = pk;
      }
    }
  }
}

// ---------------- FFN GEMMs. MODE 0: +bias,ReLU -> bf16. MODE 1: +bias+resid -> f32 ----------------
template <int MODE>
__global__ __launch_bounds__(256) void gemm_ffn_kernel(
    const unsigned short* __restrict__ A, const unsigned short* __restrict__ Bt,
    void* __restrict__ outv, const float* __restrict__ bias, int K, int N) {
  int m0 = blockIdx.x * 128, n0 = blockIdx.y * 128;
  f32x4 acc[4][4];
  gemm_core(A, Bt, K, m0, n0, acc);
  int lane = threadIdx.x & 63, wid = threadIdx.x >> 6;
  int wm = (wid & 1) * 64, wn = (wid >> 1) * 64, lm = lane & 15, lq = lane >> 4;
#pragma unroll
  for (int mi = 0; mi < 4; ++mi) {
    int rowb = m0 + wm + mi * 16 + lq * 4;
#pragma unroll
    for (int ni = 0; ni < 4; ++ni) {
      int col = n0 + wn + ni * 16 + lm;
      float bsv = bias[col];
#pragma unroll
      for (int r = 0; r < 4; ++r) {
        long idx = (long)(rowb + r) * N + col;
        float v = acc[mi][ni][r] + bsv;
        if (MODE == 0) {
          ((unsigned short*)outv)[idx] = f32_bf16(v > 0.f ? v : 0.f);
        } else {
          float* o = (float*)outv;
          o[idx] = o[idx] + v;
        }
      }
    }
  }
}

// ---------------- Flash attention v4: 64 q-rows/block, 4 waves x 16 rows ----------------
// 40KB LDS (XOR granule swizzle, no padding) -> 4 blocks/CU = 16 waves/CU.
// Heavy-first causal scheduling (bxx reversed). Per-lane partial row-sums (lr) with
// one epilogue reduce. Rescale skipped when no row max grows (uniform __any branch).
// Epilogue: LDS transpose -> float4 full-line stores (kills partial-line writeback).
__global__ __launch_bounds__(256, 4) void attn_kernel(
    const unsigned short* __restrict__ Qb, const unsigned short* __restrict__ Kb,
    const unsigned short* __restrict__ VTb, float* __restrict__ Ob) {
  __shared__ __align__(16) char smem[40960];
  unsigned short* sK = (unsigned short*)smem;            // 64x128 bf16, swizzled
  unsigned short* sV = (unsigned short*)(smem + 16384);  // 128x64 bf16, swizzled
  unsigned short* sP = (unsigned short*)(smem + 32768);  // 4 waves x 16x64, swizzled
  const int tid = threadIdx.x, lane = tid & 63, wid = tid >> 6;
  const int lm = lane & 15, lq = lane >> 4;
  // XCD-bijective swizzle; heavy blocks (large bxx -> many k-tiles) launch FIRST
  int flat = blockIdx.x;
  int swz = (flat & 7) * 256 + (flat >> 3);
  int bxx = 31 - (swz & 31);
  int h = (swz >> 5) & 15;
  int b = swz >> 9;
  const int q0 = bxx * 64;
  const long bh = (long)(b * NHEAD + h);
  const unsigned short* qp = Qb + (bh * TLEN + q0 + wid * 16) * HDIM;
  const unsigned short* kp = Kb + bh * TLEN * HDIM;
  const unsigned short* vp = VTb + bh * HDIM * TLEN;
  unsigned short* pw = sP + wid * 1024;  // 16x64
  bf16x8 qf[4];
#pragma unroll
  for (int c = 0; c < 4; ++c)
    qf[c] = *(const bf16x8*)(qp + (long)lm * HDIM + c * 32 + lq * 8);
  f32x4 oacc[8];
#pragma unroll
  for (int c = 0; c < 8; ++c) oacc[c] = (f32x4){0.f, 0.f, 0.f, 0.f};
  float mr[4], lr[4];
#pragma unroll
  for (int r = 0; r < 4; ++r) { mr[r] = -3.0e38f; lr[r] = 0.f; }
  const float sl = 0.08838834764831845f * 1.4426950408889634f;  // scale * log2(e)
  const int nk = bxx + 1;
  uint4 kreg[4], vreg[4];
  // prefetch tile 0 into registers
#pragma unroll
  for (int i = 0; i < 4; ++i) {
    int id = i * 256 + tid;
    kreg[i] = *(const uint4*)(kp + (long)(id >> 4) * HDIM + (id & 15) * 8);
    vreg[i] = *(const uint4*)(vp + (long)(id >> 3) * TLEN + (id & 7) * 8);
  }
  for (int it = 0; it < nk; ++it) {
    const int kb = it * 64;
    __syncthreads();  // prior-iter LDS reads complete before overwrite
    // staged regs -> LDS (XOR granule swizzle: linear global src, swizzled dest)
#pragma unroll
    for (int i = 0; i < 4; ++i) {
      int id = i * 256 + tid;
      int krow = id >> 4, kg = (id & 15) ^ (krow & 7);
      *(uint4*)(&sK[krow * 128 + kg * 8]) = kreg[i];
      int vrow = id >> 3, vg = (id & 7) ^ (vrow & 7);
      *(uint4*)(&sV[vrow * 64 + vg * 8]) = vreg[i];
    }
    // issue next tile's global loads; latency hides under QK+softmax+PV
    if (it + 1 < nk) {
      const int kn = kb + 64;
#pragma unroll
      for (int i = 0; i < 4; ++i) {
        int id = i * 256 + tid;
        kreg[i] = *(const uint4*)(kp + (long)(kn + (id >> 4)) * HDIM + (id & 15) * 8);
        vreg[i] = *(const uint4*)(vp + (long)(id >> 3) * TLEN + kn + (id & 7) * 8);
      }
    }
    __syncthreads();  // tile visible to all waves
    // QK^T: S[16x64] per wave
    f32x4 s[4];
#pragma unroll
    for (int ni = 0; ni < 4; ++ni) s[ni] = (f32x4){0.f, 0.f, 0.f, 0.f};
    __builtin_amdgcn_s_setprio(1);
#pragma unroll
    for (int c = 0; c < 4; ++c) {
      bf16x8 bk[4];
#pragma unroll
      for (int ni = 0; ni < 4; ++ni) {
        int row = ni * 16 + lm;
        int g = (c * 4 + lq) ^ (row & 7);
        bk[ni] = *(const bf16x8*)(&sK[row * 128 + g * 8]);
      }
#pragma unroll
      for (int ni = 0; ni < 4; ++ni)
        s[ni] = __builtin_amdgcn_mfma_f32_16x16x32_bf16(qf[c], bk[ni], s[ni], 0, 0, 0);
    }
    __builtin_amdgcn_s_setprio(0);
    // online softmax in log2-scaled domain (rows lq*4+r, cols kb+ni*16+lm)
    const bool diag = (it == nk - 1);
    float v[4][4], mx[4];
#pragma unroll
    for (int r = 0; r < 4; ++r) {
      int qrow = q0 + wid * 16 + lq * 4 + r;
      float m = -3.0e38f;
#pragma unroll
      for (int ni = 0; ni < 4; ++ni) {
        float t = s[ni][r] * sl;
        if (diag && (kb + ni * 16 + lm > qrow)) t = -3.0e38f;
        v[r][ni] = t;
        m = fmaxf(m, t);
      }
#pragma unroll
      for (int off = 8; off >= 1; off >>= 1) m = fmaxf(m, __shfl_xor(m, off));
      mx[r] = m;
    }
    bool grew = (mx[0] > mr[0]) | (mx[1] > mr[1]) | (mx[2] > mr[2]) | (mx[3] > mr[3]);
    if (__any(grew)) {
#pragma unroll
      for (int r = 0; r < 4; ++r) {
        float mn = fmaxf(mr[r], mx[r]);
        float a = exp2f(mr[r] - mn);
        mr[r] = mn;
        lr[r] *= a;
#pragma unroll
        for (int c = 0; c < 8; ++c) oacc[c][r] *= a;
      }
    }
#pragma unroll
    for (int r = 0; r < 4; ++r) {
      int prow = lq * 4 + r;
      float rs = 0.f;
#pragma unroll
      for (int ni = 0; ni < 4; ++ni) {
        float p = exp2f(v[r][ni] - mr[r]);
        rs += p;
        pw[prow * 64 + ((ni * 16 + lm) ^ ((prow & 7) << 3))] = f32_bf16(p);
      }
      lr[r] += rs;  // per-lane partial; reduced once at epilogue
    }
    __asm__ volatile("s_waitcnt lgkmcnt(0)" ::: "memory");  // own-wave P visible
    // PV: O[16x128] += P[16x64] * V[64x128]
    __builtin_amdgcn_s_setprio(1);
#pragma unroll
    for (int kc = 0; kc < 2; ++kc) {
      bf16x8 pf = *(const bf16x8*)(&sP[wid * 1024 + lm * 64 + ((kc * 32 + lq * 8) ^ ((lm & 7) << 3))]);
#pragma unroll
      for (int c = 0; c < 8; ++c) {
        int row = c * 16 + lm;
        int g = (kc * 4 + lq) ^ (row & 7);
        bf16x8 vf = *(const bf16x8*)(&sV[row * 64 + g * 8]);
        oacc[c] = __builtin_amdgcn_mfma_f32_16x16x32_bf16(pf, vf, oacc[c], 0, 0, 0);
      }
    }
    __builtin_amdgcn_s_setprio(0);
  }
  // epilogue: reduce lr, LDS transpose, coalesced float4 stores
  __syncthreads();
#pragma unroll
  for (int r = 0; r < 4; ++r) {
#pragma unroll
    for (int off = 8; off >= 1; off >>= 1) lr[r] += __shfl_xor(lr[r], off);
  }
  float inv[4];
#pragma unroll
  for (int r = 0; r < 4; ++r) inv[r] = 1.f / lr[r];
  float* sO = (float*)smem;  // 64 x 132 f32 = 33792 B
#pragma unroll
  for (int c = 0; c < 8; ++c)
#pragma unroll
    for (int r = 0; r < 4; ++r)
      sO[(wid * 16 + lq * 4 + r) * 132 + c * 16 + lm] = oacc[c][r] * inv[r];
  __syncthreads();
  float* ob = Ob + ((long)b * TLEN + q0) * DDIM + (long)h * HDIM;
#pragma unroll
  for (int i = 0; i < 8; ++i) {
    int idx = i * 256 + tid;
    int row = idx >> 5, c4 = (idx & 31) * 4;
    *(float4*)(ob + (long)row * DDIM + c4) = *(const float4*)(&sO[row * 132 + c4]);
  }
}

// ---------------- launch ----------------
extern "C" void kernel_launch(void* const* d_in, const int* in_sizes, int n_in,
                              void* d_out, int out_size, void* d_ws, size_t ws_size,
                              hipStream_t stream) {
  const float* x   = (const float*)d_in[0];
  const float* Wq  = (const float*)d_in[1];
  const float* bq  = (const float*)d_in[2];
  const float* Wk  = (const float*)d_in[3];
  const float* bk  = (const float*)d_in[4];
  const float* Wv  = (const float*)d_in[5];
  const float* bv  = (const float*)d_in[6];
  const float* W1  = (const float*)d_in[7];
  const float* b1  = (const float*)d_in[8];
  const float* W2  = (const float*)d_in[9];
  const float* b2  = (const float*)d_in[10];
  const float* g1  = (const float*)d_in[11];
  const float* be1 = (const float*)d_in[12];
  const float* g2  = (const float*)d_in[13];
  const float* be2 = (const float*)d_in[14];
  float* out = (float*)d_out;
  char* ws = (char*)d_ws;
  // ws layout (152 MiB): [0,24M) wtqkv | [24M,56M) qb->ff1buf | [56M,88M) kbuf->wt1
  //                      | [88M,120M) vtb->wt2 | [120M,152M) hbf
  unsigned short* wtqkv  = (unsigned short*)(ws + 0L);
  unsigned short* qb     = (unsigned short*)(ws + 25165824L);
  unsigned short* kbuf   = (unsigned short*)(ws + 58720256L);
  unsigned short* vtb    = (unsigned short*)(ws + 92274688L);
  unsigned short* hbf    = (unsigned short*)(ws + 125829120L);
  unsigned short* ff1buf = qb;
  unsigned short* wt1    = kbuf;
  unsigned short* wt2    = vtb;

  dim3 blk(256);
  transpose_bf16_kernel<<<dim3(4, 64, 16), blk, 0, stream>>>(Wq, wtqkv, 2048, 128, 2048L * 128, 2048L * 128);
  transpose_bf16_kernel<<<dim3(4, 64, 16), blk, 0, stream>>>(Wk, wtqkv + 2048L * 2048, 2048, 128, 2048L * 128, 2048L * 128);
  transpose_bf16_kernel<<<dim3(4, 64, 16), blk, 0, stream>>>(Wv, wtqkv + 2L * 2048 * 2048, 2048, 128, 2048L * 128, 2048L * 128);

  ln_kernel<<<dim3(8192), blk, 0, stream>>>(x, g1, be1, hbf);
  gemm_qkv_kernel<<<dim3(64, 16, 3), blk, 0, stream>>>(hbf, wtqkv, qb, kbuf, vtb, bq, bk, bv);
  attn_kernel<<<dim3(2048), blk, 0, stream>>>(qb, kbuf, vtb, out);

  transpose_bf16_kernel<<<dim3(256, 64, 1), blk, 0, stream>>>(W1, wt1, 2048, 8192, 0, 0);
  transpose_bf16_kernel<<<dim3(64, 256, 1), blk, 0, stream>>>(W2, wt2, 8192, 2048, 0, 0);

  resid_ln_kernel<<<dim3(8192), blk, 0, stream>>>(x, out, g2, be2, hbf);

  for (int c = 0; c < 4; ++c) {
    gemm_ffn_kernel<0><<<dim3(16, 64), blk, 0, stream>>>(
        hbf + (long)c * 2048 * DDIM, wt1, ff1buf, b1, DDIM, 4 * DDIM);
    gemm_ffn_kernel<1><<<dim3(16, 16), blk, 0, stream>>>(
        ff1buf, wt2, out + (long)c * 2048 * DDIM, b2, 4 * DDIM, DDIM);
  }
}

// Round 3
// 1716.961 us; speedup vs baseline: 1.2122x; 1.2122x over previous
//
#include <hip/hip_runtime.h>
#include <stdint.h>

#define TLEN 2048
#define DDIM 2048
#define NHEAD 16
#define HDIM 128
#define BSZ 4

typedef short bf16x8 __attribute__((ext_vector_type(8)));
typedef float f32x4 __attribute__((ext_vector_type(4)));

__device__ __forceinline__ unsigned short f32_bf16(float f) {
  union { float f; unsigned int u; } v; v.f = f;
  unsigned int u = v.u;
  unsigned int r = (u + 0x7fffu + ((u >> 16) & 1u)) >> 16;
  return (unsigned short)r;
}

// async 16B global->LDS (dest = wave-uniform base + lane*16)
__device__ __forceinline__ void async_cp16(const void* g, void* l) {
  __builtin_amdgcn_global_load_lds(
      (const __attribute__((address_space(1))) unsigned int*)g,
      (__attribute__((address_space(3))) unsigned int*)l, 16, 0, 0);
}

// ---------------- weight transpose + f32->bf16 convert ----------------
__global__ __launch_bounds__(256) void transpose_bf16_kernel(
    const float* __restrict__ in, unsigned short* __restrict__ out,
    int R, int C, long in_z, long out_z) {
  __shared__ float tile[32][33];
  in += (long)blockIdx.z * in_z;
  out += (long)blockIdx.z * out_z;
  int c0 = blockIdx.x * 32, r0 = blockIdx.y * 32;
  int cr = threadIdx.x & 31, rr = threadIdx.x >> 5;
#pragma unroll
  for (int i = 0; i < 4; ++i)
    tile[rr + i * 8][cr] = in[(long)(r0 + rr + i * 8) * C + c0 + cr];
  __syncthreads();
#pragma unroll
  for (int i = 0; i < 4; ++i)
    out[(long)(c0 + rr + i * 8) * R + r0 + cr] = f32_bf16(tile[cr][rr + i * 8]);
}

// ---------------- block reduction helper (sum, sumsq) ----------------
__device__ __forceinline__ void block_reduce2(float& s, float& q) {
#pragma unroll
  for (int off = 32; off >= 1; off >>= 1) {
    s += __shfl_xor(s, off);
    q += __shfl_xor(q, off);
  }
  __shared__ float rs[4], rq[4];
  int lane = threadIdx.x & 63, wid = threadIdx.x >> 6;
  if (lane == 0) { rs[wid] = s; rq[wid] = q; }
  __syncthreads();
  s = rs[0] + rs[1] + rs[2] + rs[3];
  q = rq[0] + rq[1] + rq[2] + rq[3];
}

// ---------------- LN1: x -> bf16 normalized ----------------
__global__ __launch_bounds__(256) void ln_kernel(
    const float* __restrict__ x, const float* __restrict__ g,
    const float* __restrict__ be, unsigned short* __restrict__ hb) {
  int row = blockIdx.x, tid = threadIdx.x;
  const float* xr = x + (long)row * DDIM;
  float4 v0 = *(const float4*)(xr + tid * 4);
  float4 v1 = *(const float4*)(xr + 1024 + tid * 4);
  float s = v0.x + v0.y + v0.z + v0.w + v1.x + v1.y + v1.z + v1.w;
  float q = v0.x * v0.x + v0.y * v0.y + v0.z * v0.z + v0.w * v0.w +
            v1.x * v1.x + v1.y * v1.y + v1.z * v1.z + v1.w * v1.w;
  block_reduce2(s, q);
  float mu = s * (1.0f / DDIM);
  float var = q * (1.0f / DDIM) - mu * mu;
  float rstd = rsqrtf(var + 1e-5f);
  float4 g0 = *(const float4*)(g + tid * 4);
  float4 g1v = *(const float4*)(g + 1024 + tid * 4);
  float4 b0 = *(const float4*)(be + tid * 4);
  float4 b1v = *(const float4*)(be + 1024 + tid * 4);
  ushort4 o0, o1;
  o0.x = f32_bf16((v0.x - mu) * rstd * g0.x + b0.x);
  o0.y = f32_bf16((v0.y - mu) * rstd * g0.y + b0.y);
  o0.z = f32_bf16((v0.z - mu) * rstd * g0.z + b0.z);
  o0.w = f32_bf16((v0.w - mu) * rstd * g0.w + b0.w);
  o1.x = f32_bf16((v1.x - mu) * rstd * g1v.x + b1v.x);
  o1.y = f32_bf16((v1.y - mu) * rstd * g1v.y + b1v.y);
  o1.z = f32_bf16((v1.z - mu) * rstd * g1v.z + b1v.z);
  o1.w = f32_bf16((v1.w - mu) * rstd * g1v.w + b1v.w);
  *(ushort4*)(hb + (long)row * DDIM + tid * 4) = o0;
  *(ushort4*)(hb + (long)row * DDIM + 1024 + tid * 4) = o1;
}

// ---------------- residual + LN2 (IN PLACE on xa==d_out) ----------------
__global__ __launch_bounds__(256) void resid_ln_kernel(
    const float* __restrict__ x, float* xa,
    const float* __restrict__ g, const float* __restrict__ be,
    unsigned short* __restrict__ hb) {
  int row = blockIdx.x, tid = threadIdx.x;
  const float* xr = x + (long)row * DDIM;
  float* ar = xa + (long)row * DDIM;
  float4 v0 = *(const float4*)(xr + tid * 4);
  float4 a0 = *(const float4*)(ar + tid * 4);
  float4 v1 = *(const float4*)(xr + 1024 + tid * 4);
  float4 a1 = *(const float4*)(ar + 1024 + tid * 4);
  v0.x += a0.x; v0.y += a0.y; v0.z += a0.z; v0.w += a0.w;
  v1.x += a1.x; v1.y += a1.y; v1.z += a1.z; v1.w += a1.w;
  *(float4*)(ar + tid * 4) = v0;
  *(float4*)(ar + 1024 + tid * 4) = v1;
  float s = v0.x + v0.y + v0.z + v0.w + v1.x + v1.y + v1.z + v1.w;
  float q = v0.x * v0.x + v0.y * v0.y + v0.z * v0.z + v0.w * v0.w +
            v1.x * v1.x + v1.y * v1.y + v1.z * v1.z + v1.w * v1.w;
  block_reduce2(s, q);
  float mu = s * (1.0f / DDIM);
  float var = q * (1.0f / DDIM) - mu * mu;
  float rstd = rsqrtf(var + 1e-5f);
  float4 g0 = *(const float4*)(g + tid * 4);
  float4 g1v = *(const float4*)(g + 1024 + tid * 4);
  float4 b0 = *(const float4*)(be + tid * 4);
  float4 b1v = *(const float4*)(be + 1024 + tid * 4);
  ushort4 o0, o1;
  o0.x = f32_bf16((v0.x - mu) * rstd * g0.x + b0.x);
  o0.y = f32_bf16((v0.y - mu) * rstd * g0.y + b0.y);
  o0.z = f32_bf16((v0.z - mu) * rstd * g0.z + b0.z);
  o0.w = f32_bf16((v0.w - mu) * rstd * g0.w + b0.w);
  o1.x = f32_bf16((v1.x - mu) * rstd * g1v.x + b1v.x);
  o1.y = f32_bf16((v1.y - mu) * rstd * g1v.y + b1v.y);
  o1.z = f32_bf16((v1.z - mu) * rstd * g1v.z + b1v.z);
  o1.w = f32_bf16((v1.w - mu) * rstd * g1v.w + b1v.w);
  *(ushort4*)(hb + (long)row * DDIM + tid * 4) = o0;
  *(ushort4*)(hb + (long)row * DDIM + 1024 + tid * 4) = o1;
}

// ---------------- MFMA GEMM core v2: global_load_lds + XOR swizzle ----------------
__device__ __forceinline__ void gemm_core(const unsigned short* __restrict__ A,
                                          const unsigned short* __restrict__ Bt,
                                          int K, int m0, int n0,
                                          f32x4 acc[4][4]) {
  __shared__ unsigned short sA[128 * 64];
  __shared__ unsigned short sB[128 * 64];
  const int tid = threadIdx.x;
  const int lane = tid & 63, wid = tid >> 6;
  const int wm = (wid & 1) * 64, wn = (wid >> 1) * 64;
  const int lm = lane & 15, lq = lane >> 4;
#pragma unroll
  for (int mi = 0; mi < 4; ++mi)
#pragma unroll
    for (int ni = 0; ni < 4; ++ni)
      acc[mi][ni] = (f32x4){0.f, 0.f, 0.f, 0.f};
  const int rbase = wid * 32;
  const int ri = lane >> 3;
  const int kgl = lane & 7;
  const int nk = K >> 6;
  for (int kt = 0; kt < nk; ++kt) {
    const unsigned short* Ak = A + (long)m0 * K + (long)kt * 64;
    const unsigned short* Bk = Bt + (long)n0 * K + (long)kt * 64;
#pragma unroll
    for (int ins = 0; ins < 4; ++ins) {
      int row = rbase + ins * 8 + ri;
      int kg = kgl ^ (row & 7);
      async_cp16(Ak + (long)row * K + kg * 8, &sA[(rbase + ins * 8) * 64]);
      async_cp16(Bk + (long)row * K + kg * 8, &sB[(rbase + ins * 8) * 64]);
    }
    __syncthreads();
#pragma unroll
    for (int kc = 0; kc < 2; ++kc) {
      bf16x8 af[4], bfr[4];
#pragma unroll
      for (int mi = 0; mi < 4; ++mi) {
        int row = wm + mi * 16 + lm;
        int kg = (kc * 4 + lq) ^ (row & 7);
        af[mi] = *(const bf16x8*)(&sA[row * 64 + kg * 8]);
      }
#pragma unroll
      for (int ni = 0; ni < 4; ++ni) {
        int row = wn + ni * 16 + lm;
        int kg = (kc * 4 + lq) ^ (row & 7);
        bfr[ni] = *(const bf16x8*)(&sB[row * 64 + kg * 8]);
      }
#pragma unroll
      for (int mi = 0; mi < 4; ++mi)
#pragma unroll
        for (int ni = 0; ni < 4; ++ni)
          acc[mi][ni] = __builtin_amdgcn_mfma_f32_16x16x32_bf16(af[mi], bfr[ni], acc[mi][ni], 0, 0, 0);
    }
    __syncthreads();
  }
}

// ---------------- QKV projection GEMM (z: 0=Q,1=K,2=V-transposed) ----------------
__global__ __launch_bounds__(256) void gemm_qkv_kernel(
    const unsigned short* __restrict__ A, const unsigned short* __restrict__ WT,
    unsigned short* __restrict__ Qb, unsigned short* __restrict__ Kb,
    unsigned short* __restrict__ VTb,
    const float* __restrict__ bq, const float* __restrict__ bk,
    const float* __restrict__ bv) {
  int m0 = blockIdx.x * 128, n0 = blockIdx.y * 128;
  int z = blockIdx.z;
  const unsigned short* Bt = WT + (long)z * DDIM * DDIM;
  f32x4 acc[4][4];
  gemm_core(A, Bt, DDIM, m0, n0, acc);
  const float* bias = (z == 0) ? bq : (z == 1) ? bk : bv;
  int lane = threadIdx.x & 63, wid = threadIdx.x >> 6;
  int wm = (wid & 1) * 64, wn = (wid >> 1) * 64, lm = lane & 15, lq = lane >> 4;
  int h = n0 >> 7;
#pragma unroll
  for (int mi = 0; mi < 4; ++mi) {
    int rowb = m0 + wm + mi * 16 + lq * 4;
    int b = rowb >> 11, t0 = rowb & (TLEN - 1);
#pragma unroll
    for (int ni = 0; ni < 4; ++ni) {
      int col = n0 + wn + ni * 16 + lm;
      int e = col & (HDIM - 1);
      float bsv = bias[col];
      if (z < 2) {
        unsigned short* o = (z == 0) ? Qb : Kb;
        long base = ((long)(b * NHEAD + h) * TLEN + t0) * HDIM + e;
#pragma unroll
        for (int r = 0; r < 4; ++r)
          o[base + (long)r * HDIM] = f32_bf16(acc[mi][ni][r] + bsv);
      } else {
        long base = ((long)(b * NHEAD + h) * HDIM + e) * TLEN + t0;
        ushort4 pk;
        pk.x = f32_bf16(acc[mi][ni][0] + bsv);
        pk.y = f32_bf16(acc[mi][ni][1] + bsv);
        pk.z = f32_bf16(acc[mi][ni][2] + bsv);
        pk.w = f32_bf16(acc[mi][ni][3] + bsv);
        *(ushort4*)(VTb + base) = pk;
      }
    }
  }
}

// ---------------- FFN GEMMs. MODE 0: +bias,ReLU -> bf16. MODE 1: +bias+resid -> f32 ----------------
template <int MODE>
__global__ __launch_bounds__(256) void gemm_ffn_kernel(
    const unsigned short* __restrict__ A, const unsigned short* __restrict__ Bt,
    void* __restrict__ outv, const float* __restrict__ bias, int K, int N) {
  int m0 = blockIdx.x * 128, n0 = blockIdx.y * 128;
  f32x4 acc[4][4];
  gemm_core(A, Bt, K, m0, n0, acc);
  int lane = threadIdx.x & 63, wid = threadIdx.x >> 6;
  int wm = (wid & 1) * 64, wn = (wid >> 1) * 64, lm = lane & 15, lq = lane >> 4;
#pragma unroll
  for (int mi = 0; mi < 4; ++mi) {
    int rowb = m0 + wm + mi * 16 + lq * 4;
#pragma unroll
    for (int ni = 0; ni < 4; ++ni) {
      int col = n0 + wn + ni * 16 + lm;
      float bsv = bias[col];
#pragma unroll
      for (int r = 0; r < 4; ++r) {
        long idx = (long)(rowb + r) * N + col;
        float v = acc[mi][ni][r] + bsv;
        if (MODE == 0) {
          ((unsigned short*)outv)[idx] = f32_bf16(v > 0.f ? v : 0.f);
        } else {
          float* o = (float*)outv;
          o[idx] = o[idx] + v;
        }
      }
    }
  }
}

// ---------------- Flash attention v5: async global_load_lds pipeline ----------------
// K double-buffered (2x16KB), V single-buffered (16KB), P overlays consumed K buffer.
// 48KB LDS -> 3 blocks/CU; no VGPR staging -> no spill (R1/R2's 1GB WRITE_SIZE).
// Raw s_barrier + counted vmcnt keep K(t+1)/V(t) loads in flight across barriers
// (__syncthreads would drain vmcnt to 0). Per iter:
//   vmcnt(0)[K(t) landed] -> barrier -> issue V(t),K(t+1) -> QK -> softmax
//   -> vmcnt(4)[V landed, K(t+1) in flight] -> barrier -> P overlay -> lgkmcnt -> PV
__global__ __launch_bounds__(256, 3) void attn_kernel(
    const unsigned short* __restrict__ Qb, const unsigned short* __restrict__ Kb,
    const unsigned short* __restrict__ VTb, float* __restrict__ Ob) {
  __shared__ __align__(16) char smem[49152];
  unsigned short* kbuf0 = (unsigned short*)smem;            // 64x128 bf16
  unsigned short* kbuf1 = (unsigned short*)(smem + 16384);  // 64x128 bf16
  unsigned short* sV = (unsigned short*)(smem + 32768);     // 128x64 bf16
  const int tid = threadIdx.x, lane = tid & 63, wid = tid >> 6;
  const int lm = lane & 15, lq = lane >> 4;
  // XCD-chunked swizzle (R1's L2-friendly grouping) + within-group heavy/light
  // interleave (LPT tail fix that preserves the single-(b,h) working set).
  int flat = blockIdx.x;
  int swz = (flat & 7) * 256 + (flat >> 3);
  int m5 = swz & 31;
  int bxx = (m5 & 1) ? (m5 >> 1) : (31 - (m5 >> 1));
  int h = (swz >> 5) & 15;
  int b = swz >> 9;
  const int q0 = bxx * 64;
  const long bh = (long)(b * NHEAD + h);
  const unsigned short* qp = Qb + (bh * TLEN + q0 + wid * 16) * HDIM;
  const unsigned short* kp = Kb + bh * TLEN * HDIM;
  const unsigned short* vp = VTb + bh * HDIM * TLEN;
  bf16x8 qf[4];
#pragma unroll
  for (int c = 0; c < 4; ++c)
    qf[c] = *(const bf16x8*)(qp + (long)lm * HDIM + c * 32 + lq * 8);
  f32x4 oacc[8];
#pragma unroll
  for (int c = 0; c < 8; ++c) oacc[c] = (f32x4){0.f, 0.f, 0.f, 0.f};
  float mr[4], lr[4];
#pragma unroll
  for (int r = 0; r < 4; ++r) { mr[r] = -3.0e38f; lr[r] = 0.f; }
  const float sl = 0.08838834764831845f * 1.4426950408889634f;  // scale * log2(e)
  const int nk = bxx + 1;
  const int kri = lane >> 4, krg = lane & 15;   // K stage: 4 rows x 16 granules
  const int vri = lane >> 3, vrg = lane & 7;    // V stage: 8 rows x 8 granules
  // prologue: issue K[0] (4 cp16/wave; wave w stages rows [w*16, w*16+16))
#pragma unroll
  for (int i = 0; i < 4; ++i) {
    int row = wid * 16 + i * 4 + kri;
    async_cp16(kp + (long)row * HDIM + (krg ^ (row & 7)) * 8,
               kbuf0 + (wid * 16 + i * 4) * 128);
  }
  for (int it = 0; it < nk; ++it) {
    const int kb = it * 64;
    unsigned short* kc_ = (it & 1) ? kbuf1 : kbuf0;
    unsigned short* kn_ = (it & 1) ? kbuf0 : kbuf1;
    // K[t] landed (only K[t] outstanding here); barrier also closes prev PV reads
    __asm__ volatile("s_waitcnt vmcnt(0)" ::: "memory");
    __asm__ volatile("s_barrier" ::: "memory");
    // issue V[t] (sV free: prev PV done) and K[t+1] (kn_ free: P(t-1) dead)
#pragma unroll
    for (int i = 0; i < 4; ++i) {
      int row = wid * 32 + i * 8 + vri;
      async_cp16(vp + (long)row * TLEN + kb + (vrg ^ (row & 7)) * 8,
                 sV + (wid * 32 + i * 8) * 64);
    }
    if (it + 1 < nk) {
      const unsigned short* kp1 = kp + (long)(kb + 64) * HDIM;
#pragma unroll
      for (int i = 0; i < 4; ++i) {
        int row = wid * 16 + i * 4 + kri;
        async_cp16(kp1 + (long)row * HDIM + (krg ^ (row & 7)) * 8,
                   kn_ + (wid * 16 + i * 4) * 128);
      }
    }
    // QK^T: S[16x64] per wave
    f32x4 s[4];
#pragma unroll
    for (int ni = 0; ni < 4; ++ni) s[ni] = (f32x4){0.f, 0.f, 0.f, 0.f};
    __builtin_amdgcn_s_setprio(1);
#pragma unroll
    for (int c = 0; c < 4; ++c) {
      bf16x8 bk[4];
#pragma unroll
      for (int ni = 0; ni < 4; ++ni) {
        int row = ni * 16 + lm;
        int g = (c * 4 + lq) ^ (row & 7);
        bk[ni] = *(const bf16x8*)(&kc_[row * 128 + g * 8]);
      }
#pragma unroll
      for (int ni = 0; ni < 4; ++ni)
        s[ni] = __builtin_amdgcn_mfma_f32_16x16x32_bf16(qf[c], bk[ni], s[ni], 0, 0, 0);
    }
    __builtin_amdgcn_s_setprio(0);
    // online softmax (rows lq*4+r, cols kb+ni*16+lm); mask only on diagonal tile
    const bool diag = (it == nk - 1);
    float v[4][4], mx[4];
#pragma unroll
    for (int r = 0; r < 4; ++r) {
      int qrow = q0 + wid * 16 + lq * 4 + r;
      float m = -3.0e38f;
#pragma unroll
      for (int ni = 0; ni < 4; ++ni) {
        float t = s[ni][r] * sl;
        if (diag && (kb + ni * 16 + lm > qrow)) t = -3.0e38f;
        v[r][ni] = t;
        m = fmaxf(m, t);
      }
#pragma unroll
      for (int off = 8; off >= 1; off >>= 1) m = fmaxf(m, __shfl_xor(m, off));
      mx[r] = m;
    }
    bool grew = (mx[0] > mr[0]) | (mx[1] > mr[1]) | (mx[2] > mr[2]) | (mx[3] > mr[3]);
    if (__any(grew)) {
#pragma unroll
      for (int r = 0; r < 4; ++r) {
        float mn = fmaxf(mr[r], mx[r]);
        float a = exp2f(mr[r] - mn);
        mr[r] = mn;
        lr[r] *= a;
#pragma unroll
        for (int c = 0; c < 8; ++c) oacc[c][r] *= a;
      }
    }
    float p[4][4];
#pragma unroll
    for (int r = 0; r < 4; ++r) {
      float rs = 0.f;
#pragma unroll
      for (int ni = 0; ni < 4; ++ni) {
        p[r][ni] = exp2f(v[r][ni] - mr[r]);
        rs += p[r][ni];
      }
      lr[r] += rs;  // per-lane partial; reduced once at epilogue
    }
    // V[t] landed (K[t+1]: 4 loads still in flight); barrier closes QK reads of kc_
    if (it + 1 < nk) {
      __asm__ volatile("s_waitcnt vmcnt(4)" ::: "memory");
    } else {
      __asm__ volatile("s_waitcnt vmcnt(0)" ::: "memory");
    }
    __asm__ volatile("s_barrier" ::: "memory");
    // P overlay into consumed K buffer (per-wave 16x64 region)
    unsigned short* pw = kc_ + wid * 1024;
#pragma unroll
    for (int r = 0; r < 4; ++r) {
      int prow = lq * 4 + r;
#pragma unroll
      for (int ni = 0; ni < 4; ++ni)
        pw[prow * 64 + ((ni * 16 + lm) ^ ((prow & 7) << 3))] = f32_bf16(p[r][ni]);
    }
    __asm__ volatile("s_waitcnt lgkmcnt(0)" ::: "memory");  // own-wave P visible
    __builtin_amdgcn_sched_barrier(0);
    // PV: O[16x128] += P[16x64] * V[64x128]
    __builtin_amdgcn_s_setprio(1);
#pragma unroll
    for (int kc = 0; kc < 2; ++kc) {
      bf16x8 pf = *(const bf16x8*)(&pw[lm * 64 + ((kc * 32 + lq * 8) ^ ((lm & 7) << 3))]);
#pragma unroll
      for (int c = 0; c < 8; ++c) {
        int row = c * 16 + lm;
        int g = (kc * 4 + lq) ^ (row & 7);
        bf16x8 vf = *(const bf16x8*)(&sV[row * 64 + g * 8]);
        oacc[c] = __builtin_amdgcn_mfma_f32_16x16x32_bf16(pf, vf, oacc[c], 0, 0, 0);
      }
    }
    __builtin_amdgcn_s_setprio(0);
  }
  // epilogue: reduce lr, LDS transpose, coalesced float4 stores
  __syncthreads();
#pragma unroll
  for (int r = 0; r < 4; ++r) {
#pragma unroll
    for (int off = 8; off >= 1; off >>= 1) lr[r] += __shfl_xor(lr[r], off);
  }
  float inv[4];
#pragma unroll
  for (int r = 0; r < 4; ++r) inv[r] = 1.f / lr[r];
  float* sO = (float*)smem;  // 64 x 132 f32 = 33792 B (fits in 48K)
#pragma unroll
  for (int c = 0; c < 8; ++c)
#pragma unroll
    for (int r = 0; r < 4; ++r)
      sO[(wid * 16 + lq * 4 + r) * 132 + c * 16 + lm] = oacc[c][r] * inv[r];
  __syncthreads();
  float* ob = Ob + ((long)b * TLEN + q0) * DDIM + (long)h * HDIM;
#pragma unroll
  for (int i = 0; i < 8; ++i) {
    int idx = i * 256 + tid;
    int row = idx >> 5, c4 = (idx & 31) * 4;
    *(float4*)(ob + (long)row * DDIM + c4) = *(const float4*)(&sO[row * 132 + c4]);
  }
}

// ---------------- launch ----------------
extern "C" void kernel_launch(void* const* d_in, const int* in_sizes, int n_in,
                              void* d_out, int out_size, void* d_ws, size_t ws_size,
                              hipStream_t stream) {
  const float* x   = (const float*)d_in[0];
  const float* Wq  = (const float*)d_in[1];
  const float* bq  = (const float*)d_in[2];
  const float* Wk  = (const float*)d_in[3];
  const float* bk  = (const float*)d_in[4];
  const float* Wv  = (const float*)d_in[5];
  const float* bv  = (const float*)d_in[6];
  const float* W1  = (const float*)d_in[7];
  const float* b1  = (const float*)d_in[8];
  const float* W2  = (const float*)d_in[9];
  const float* b2  = (const float*)d_in[10];
  const float* g1  = (const float*)d_in[11];
  const float* be1 = (const float*)d_in[12];
  const float* g2  = (const float*)d_in[13];
  const float* be2 = (const float*)d_in[14];
  float* out = (float*)d_out;
  char* ws = (char*)d_ws;
  // ws layout (152 MiB): [0,24M) wtqkv | [24M,56M) qb->ff1buf | [56M,88M) kbuf->wt1
  //                      | [88M,120M) vtb->wt2 | [120M,152M) hbf
  unsigned short* wtqkv  = (unsigned short*)(ws + 0L);
  unsigned short* qb     = (unsigned short*)(ws + 25165824L);
  unsigned short* kbuf   = (unsigned short*)(ws + 58720256L);
  unsigned short* vtb    = (unsigned short*)(ws + 92274688L);
  unsigned short* hbf    = (unsigned short*)(ws + 125829120L);
  unsigned short* ff1buf = qb;
  unsigned short* wt1    = kbuf;
  unsigned short* wt2    = vtb;

  dim3 blk(256);
  transpose_bf16_kernel<<<dim3(4, 64, 16), blk, 0, stream>>>(Wq, wtqkv, 2048, 128, 2048L * 128, 2048L * 128);
  transpose_bf16_kernel<<<dim3(4, 64, 16), blk, 0, stream>>>(Wk, wtqkv + 2048L * 2048, 2048, 128, 2048L * 128, 2048L * 128);
  transpose_bf16_kernel<<<dim3(4, 64, 16), blk, 0, stream>>>(Wv, wtqkv + 2L * 2048 * 2048, 2048, 128, 2048L * 128, 2048L * 128);

  ln_kernel<<<dim3(8192), blk, 0, stream>>>(x, g1, be1, hbf);
  gemm_qkv_kernel<<<dim3(64, 16, 3), blk, 0, stream>>>(hbf, wtqkv, qb, kbuf, vtb, bq, bk, bv);
  attn_kernel<<<dim3(2048), blk, 0, stream>>>(qb, kbuf, vtb, out);

  transpose_bf16_kernel<<<dim3(256, 64, 1), blk, 0, stream>>>(W1, wt1, 2048, 8192, 0, 0);
  transpose_bf16_kernel<<<dim3(64, 256, 1), blk, 0, stream>>>(W2, wt2, 8192, 2048, 0, 0);

  resid_ln_kernel<<<dim3(8192), blk, 0, stream>>>(x, out, g2, be2, hbf);

  for (int c = 0; c < 4; ++c) {
    gemm_ffn_kernel<0><<<dim3(16, 64), blk, 0, stream>>>(
        hbf + (long)c * 2048 * DDIM, wt1, ff1buf, b1, DDIM, 4 * DDIM);
    gemm_ffn_kernel<1><<<dim3(16, 16), blk, 0, stream>>>(
        ff1buf, wt2, out + (long)c * 2048 * DDIM, b2, 4 * DDIM, DDIM);
  }
}

// Round 5
// 1527.178 us; speedup vs baseline: 1.3628x; 1.1243x over previous
//
#include <hip/hip_runtime.h>
#include <stdint.h>

#define TLEN 2048
#define DDIM 2048
#define NHEAD 16
#define HDIM 128
#define BSZ 4

typedef short bf16x8 __attribute__((ext_vector_type(8)));
typedef float f32x4 __attribute__((ext_vector_type(4)));

__device__ __forceinline__ unsigned short f32_bf16(float f) {
  union { float f; unsigned int u; } v; v.f = f;
  unsigned int u = v.u;
  unsigned int r = (u + 0x7fffu + ((u >> 16) & 1u)) >> 16;
  return (unsigned short)r;
}

// async 16B global->LDS (dest = wave-uniform base + lane*16)
__device__ __forceinline__ void async_cp16(const void* g, void* l) {
  __builtin_amdgcn_global_load_lds(
      (const __attribute__((address_space(1))) unsigned int*)g,
      (__attribute__((address_space(3))) unsigned int*)l, 16, 0, 0);
}

// ---------------- weight transpose + f32->bf16 convert ----------------
__global__ __launch_bounds__(256) void transpose_bf16_kernel(
    const float* __restrict__ in, unsigned short* __restrict__ out,
    int R, int C, long in_z, long out_z) {
  __shared__ float tile[32][33];
  in += (long)blockIdx.z * in_z;
  out += (long)blockIdx.z * out_z;
  int c0 = blockIdx.x * 32, r0 = blockIdx.y * 32;
  int cr = threadIdx.x & 31, rr = threadIdx.x >> 5;
#pragma unroll
  for (int i = 0; i < 4; ++i)
    tile[rr + i * 8][cr] = in[(long)(r0 + rr + i * 8) * C + c0 + cr];
  __syncthreads();
#pragma unroll
  for (int i = 0; i < 4; ++i)
    out[(long)(c0 + rr + i * 8) * R + r0 + cr] = f32_bf16(tile[cr][rr + i * 8]);
}

// ---------------- block reduction helper (sum, sumsq) ----------------
__device__ __forceinline__ void block_reduce2(float& s, float& q) {
#pragma unroll
  for (int off = 32; off >= 1; off >>= 1) {
    s += __shfl_xor(s, off);
    q += __shfl_xor(q, off);
  }
  __shared__ float rs[4], rq[4];
  int lane = threadIdx.x & 63, wid = threadIdx.x >> 6;
  if (lane == 0) { rs[wid] = s; rq[wid] = q; }
  __syncthreads();
  s = rs[0] + rs[1] + rs[2] + rs[3];
  q = rq[0] + rq[1] + rq[2] + rq[3];
}

// ---------------- LN1: x -> bf16 normalized ----------------
__global__ __launch_bounds__(256) void ln_kernel(
    const float* __restrict__ x, const float* __restrict__ g,
    const float* __restrict__ be, unsigned short* __restrict__ hb) {
  int row = blockIdx.x, tid = threadIdx.x;
  const float* xr = x + (long)row * DDIM;
  float4 v0 = *(const float4*)(xr + tid * 4);
  float4 v1 = *(const float4*)(xr + 1024 + tid * 4);
  float s = v0.x + v0.y + v0.z + v0.w + v1.x + v1.y + v1.z + v1.w;
  float q = v0.x * v0.x + v0.y * v0.y + v0.z * v0.z + v0.w * v0.w +
            v1.x * v1.x + v1.y * v1.y + v1.z * v1.z + v1.w * v1.w;
  block_reduce2(s, q);
  float mu = s * (1.0f / DDIM);
  float var = q * (1.0f / DDIM) - mu * mu;
  float rstd = rsqrtf(var + 1e-5f);
  float4 g0 = *(const float4*)(g + tid * 4);
  float4 g1v = *(const float4*)(g + 1024 + tid * 4);
  float4 b0 = *(const float4*)(be + tid * 4);
  float4 b1v = *(const float4*)(be + 1024 + tid * 4);
  ushort4 o0, o1;
  o0.x = f32_bf16((v0.x - mu) * rstd * g0.x + b0.x);
  o0.y = f32_bf16((v0.y - mu) * rstd * g0.y + b0.y);
  o0.z = f32_bf16((v0.z - mu) * rstd * g0.z + b0.z);
  o0.w = f32_bf16((v0.w - mu) * rstd * g0.w + b0.w);
  o1.x = f32_bf16((v1.x - mu) * rstd * g1v.x + b1v.x);
  o1.y = f32_bf16((v1.y - mu) * rstd * g1v.y + b1v.y);
  o1.z = f32_bf16((v1.z - mu) * rstd * g1v.z + b1v.z);
  o1.w = f32_bf16((v1.w - mu) * rstd * g1v.w + b1v.w);
  *(ushort4*)(hb + (long)row * DDIM + tid * 4) = o0;
  *(ushort4*)(hb + (long)row * DDIM + 1024 + tid * 4) = o1;
}

// ---------------- residual + LN2 (IN PLACE on xa==d_out) ----------------
__global__ __launch_bounds__(256) void resid_ln_kernel(
    const float* __restrict__ x, float* xa,
    const float* __restrict__ g, const float* __restrict__ be,
    unsigned short* __restrict__ hb) {
  int row = blockIdx.x, tid = threadIdx.x;
  const float* xr = x + (long)row * DDIM;
  float* ar = xa + (long)row * DDIM;
  float4 v0 = *(const float4*)(xr + tid * 4);
  float4 a0 = *(const float4*)(ar + tid * 4);
  float4 v1 = *(const float4*)(xr + 1024 + tid * 4);
  float4 a1 = *(const float4*)(ar + 1024 + tid * 4);
  v0.x += a0.x; v0.y += a0.y; v0.z += a0.z; v0.w += a0.w;
  v1.x += a1.x; v1.y += a1.y; v1.z += a1.z; v1.w += a1.w;
  *(float4*)(ar + tid * 4) = v0;
  *(float4*)(ar + 1024 + tid * 4) = v1;
  float s = v0.x + v0.y + v0.z + v0.w + v1.x + v1.y + v1.z + v1.w;
  float q = v0.x * v0.x + v0.y * v0.y + v0.z * v0.z + v0.w * v0.w +
            v1.x * v1.x + v1.y * v1.y + v1.z * v1.z + v1.w * v1.w;
  block_reduce2(s, q);
  float mu = s * (1.0f / DDIM);
  float var = q * (1.0f / DDIM) - mu * mu;
  float rstd = rsqrtf(var + 1e-5f);
  float4 g0 = *(const float4*)(g + tid * 4);
  float4 g1v = *(const float4*)(g + 1024 + tid * 4);
  float4 b0 = *(const float4*)(be + tid * 4);
  float4 b1v = *(const float4*)(be + 1024 + tid * 4);
  ushort4 o0, o1;
  o0.x = f32_bf16((v0.x - mu) * rstd * g0.x + b0.x);
  o0.y = f32_bf16((v0.y - mu) * rstd * g0.y + b0.y);
  o0.z = f32_bf16((v0.z - mu) * rstd * g0.z + b0.z);
  o0.w = f32_bf16((v0.w - mu) * rstd * g0.w + b0.w);
  o1.x = f32_bf16((v1.x - mu) * rstd * g1v.x + b1v.x);
  o1.y = f32_bf16((v1.y - mu) * rstd * g1v.y + b1v.y);
  o1.z = f32_bf16((v1.z - mu) * rstd * g1v.z + b1v.z);
  o1.w = f32_bf16((v1.w - mu) * rstd * g1v.w + b1v.w);
  *(ushort4*)(hb + (long)row * DDIM + tid * 4) = o0;
  *(ushort4*)(hb + (long)row * DDIM + 1024 + tid * 4) = o1;
}

// ---------------- MFMA GEMM core v3: separate A/B row strides ----------------
__device__ __forceinline__ void gemm_core(const unsigned short* __restrict__ A,
                                          const unsigned short* __restrict__ Bt,
                                          int K, int lda, int ldb, int m0, int n0,
                                          f32x4 acc[4][4]) {
  __shared__ unsigned short sA[128 * 64];
  __shared__ unsigned short sB[128 * 64];
  const int tid = threadIdx.x;
  const int lane = tid & 63, wid = tid >> 6;
  const int wm = (wid & 1) * 64, wn = (wid >> 1) * 64;
  const int lm = lane & 15, lq = lane >> 4;
#pragma unroll
  for (int mi = 0; mi < 4; ++mi)
#pragma unroll
    for (int ni = 0; ni < 4; ++ni)
      acc[mi][ni] = (f32x4){0.f, 0.f, 0.f, 0.f};
  const int rbase = wid * 32;
  const int ri = lane >> 3;
  const int kgl = lane & 7;
  const int nk = K >> 6;
  for (int kt = 0; kt < nk; ++kt) {
    const unsigned short* Ak = A + (long)m0 * lda + (long)kt * 64;
    const unsigned short* Bk = Bt + (long)n0 * ldb + (long)kt * 64;
#pragma unroll
    for (int ins = 0; ins < 4; ++ins) {
      int row = rbase + ins * 8 + ri;
      int kg = kgl ^ (row & 7);
      async_cp16(Ak + (long)row * lda + kg * 8, &sA[(rbase + ins * 8) * 64]);
      async_cp16(Bk + (long)row * ldb + kg * 8, &sB[(rbase + ins * 8) * 64]);
    }
    __syncthreads();
#pragma unroll
    for (int kc = 0; kc < 2; ++kc) {
      bf16x8 af[4], bfr[4];
#pragma unroll
      for (int mi = 0; mi < 4; ++mi) {
        int row = wm + mi * 16 + lm;
        int kg = (kc * 4 + lq) ^ (row & 7);
        af[mi] = *(const bf16x8*)(&sA[row * 64 + kg * 8]);
      }
#pragma unroll
      for (int ni = 0; ni < 4; ++ni) {
        int row = wn + ni * 16 + lm;
        int kg = (kc * 4 + lq) ^ (row & 7);
        bfr[ni] = *(const bf16x8*)(&sB[row * 64 + kg * 8]);
      }
#pragma unroll
      for (int mi = 0; mi < 4; ++mi)
#pragma unroll
        for (int ni = 0; ni < 4; ++ni)
          acc[mi][ni] = __builtin_amdgcn_mfma_f32_16x16x32_bf16(af[mi], bfr[ni], acc[mi][ni], 0, 0, 0);
    }
    __syncthreads();
  }
}

// ---------------- QKV projection GEMM (z: 0=Q,1=K,2=V-transposed) ----------------
__global__ __launch_bounds__(256) void gemm_qkv_kernel(
    const unsigned short* __restrict__ A, const unsigned short* __restrict__ WT,
    unsigned short* __restrict__ Qb, unsigned short* __restrict__ Kb,
    unsigned short* __restrict__ VTb,
    const float* __restrict__ bq, const float* __restrict__ bk,
    const float* __restrict__ bv) {
  int m0 = blockIdx.x * 128, n0 = blockIdx.y * 128;
  int z = blockIdx.z;
  const unsigned short* Bt = WT + (long)z * DDIM * DDIM;
  f32x4 acc[4][4];
  gemm_core(A, Bt, DDIM, DDIM, DDIM, m0, n0, acc);
  const float* bias = (z == 0) ? bq : (z == 1) ? bk : bv;
  int lane = threadIdx.x & 63, wid = threadIdx.x >> 6;
  int wm = (wid & 1) * 64, wn = (wid >> 1) * 64, lm = lane & 15, lq = lane >> 4;
  int h = n0 >> 7;
#pragma unroll
  for (int mi = 0; mi < 4; ++mi) {
    int rowb = m0 + wm + mi * 16 + lq * 4;
    int b = rowb >> 11, t0 = rowb & (TLEN - 1);
#pragma unroll
    for (int ni = 0; ni < 4; ++ni) {
      int col = n0 + wn + ni * 16 + lm;
      int e = col & (HDIM - 1);
      float bsv = bias[col];
      if (z < 2) {
        unsigned short* o = (z == 0) ? Qb : Kb;
        long base = ((long)(b * NHEAD + h) * TLEN + t0) * HDIM + e;
#pragma unroll
        for (int r = 0; r < 4; ++r)
          o[base + (long)r * HDIM] = f32_bf16(acc[mi][ni][r] + bsv);
      } else {
        long base = ((long)(b * NHEAD + h) * HDIM + e) * TLEN + t0;
        ushort4 pk;
        pk.x = f32_bf16(acc[mi][ni][0] + bsv);
        pk.y = f32_bf16(acc[mi][ni][1] + bsv);
        pk.z = f32_bf16(acc[mi][ni][2] + bsv);
        pk.w = f32_bf16(acc[mi][ni][3] + bsv);
        *(ushort4*)(VTb + base) = pk;
      }
    }
  }
}

// ---------------- FFN GEMMs (N-sliced, all dispatches 1024 blocks) ----------------
// MODE 0: +bias, ReLU -> bf16 (ff1 slice). MODE 1: +bias + resid accumulate -> f32.
// MODE 2: resid accumulate only -> f32 (slices 1..3).
template <int MODE>
__global__ __launch_bounds__(256) void gemm_ffn_kernel(
    const unsigned short* __restrict__ A, const unsigned short* __restrict__ Bt,
    void* __restrict__ outv, const float* __restrict__ bias,
    int K, int lda, int ldb, int N) {
  int m0 = blockIdx.x * 128, n0 = blockIdx.y * 128;
  f32x4 acc[4][4];
  gemm_core(A, Bt, K, lda, ldb, m0, n0, acc);
  int lane = threadIdx.x & 63, wid = threadIdx.x >> 6;
  int wm = (wid & 1) * 64, wn = (wid >> 1) * 64, lm = lane & 15, lq = lane >> 4;
#pragma unroll
  for (int mi = 0; mi < 4; ++mi) {
    int rowb = m0 + wm + mi * 16 + lq * 4;
#pragma unroll
    for (int ni = 0; ni < 4; ++ni) {
      int col = n0 + wn + ni * 16 + lm;
      float bsv = (MODE == 2) ? 0.f : bias[col];
#pragma unroll
      for (int r = 0; r < 4; ++r) {
        long idx = (long)(rowb + r) * N + col;
        float v = acc[mi][ni][r] + bsv;
        if (MODE == 0) {
          ((unsigned short*)outv)[idx] = f32_bf16(v > 0.f ? v : 0.f);
        } else {
          float* o = (float*)outv;
          o[idx] = o[idx] + v;
        }
      }
    }
  }
}

// ---------------- Flash attention v6: async pipeline + defer-max ----------------
// K double-buffered (2x16KB), V single-buffered (16KB), P overlays consumed K buffer.
// Raw s_barrier + counted vmcnt keep K(t+1)/V(t) loads in flight across barriers.
// Defer-max (T13, THR=8 in log2 domain): skip shuffle-max + O/l rescale unless some
// lane's local tile max exceeds mr+8; exact softmax recovered by final 1/l.
__global__ __launch_bounds__(256, 3) void attn_kernel(
    const unsigned short* __restrict__ Qb, const unsigned short* __restrict__ Kb,
    const unsigned short* __restrict__ VTb, float* __restrict__ Ob) {
  __shared__ __align__(16) char smem[49152];
  unsigned short* kbuf0 = (unsigned short*)smem;            // 64x128 bf16
  unsigned short* kbuf1 = (unsigned short*)(smem + 16384);  // 64x128 bf16
  unsigned short* sV = (unsigned short*)(smem + 32768);     // 128x64 bf16
  const int tid = threadIdx.x, lane = tid & 63, wid = tid >> 6;
  const int lm = lane & 15, lq = lane >> 4;
  int flat = blockIdx.x;
  int swz = (flat & 7) * 256 + (flat >> 3);
  int m5 = swz & 31;
  int bxx = (m5 & 1) ? (m5 >> 1) : (31 - (m5 >> 1));
  int h = (swz >> 5) & 15;
  int b = swz >> 9;
  const int q0 = bxx * 64;
  const long bh = (long)(b * NHEAD + h);
  const unsigned short* qp = Qb + (bh * TLEN + q0 + wid * 16) * HDIM;
  const unsigned short* kp = Kb + bh * TLEN * HDIM;
  const unsigned short* vp = VTb + bh * HDIM * TLEN;
  bf16x8 qf[4];
#pragma unroll
  for (int c = 0; c < 4; ++c)
    qf[c] = *(const bf16x8*)(qp + (long)lm * HDIM + c * 32 + lq * 8);
  f32x4 oacc[8];
#pragma unroll
  for (int c = 0; c < 8; ++c) oacc[c] = (f32x4){0.f, 0.f, 0.f, 0.f};
  float mr[4], lr[4];
#pragma unroll
  for (int r = 0; r < 4; ++r) { mr[r] = -3.0e38f; lr[r] = 0.f; }
  const float sl = 0.08838834764831845f * 1.4426950408889634f;  // scale * log2(e)
  const int nk = bxx + 1;
  const int kri = lane >> 4, krg = lane & 15;   // K stage: 4 rows x 16 granules
  const int vri = lane >> 3, vrg = lane & 7;    // V stage: 8 rows x 8 granules
  // prologue: issue K[0]
#pragma unroll
  for (int i = 0; i < 4; ++i) {
    int row = wid * 16 + i * 4 + kri;
    async_cp16(kp + (long)row * HDIM + (krg ^ (row & 7)) * 8,
               kbuf0 + (wid * 16 + i * 4) * 128);
  }
  for (int it = 0; it < nk; ++it) {
    const int kb = it * 64;
    unsigned short* kc_ = (it & 1) ? kbuf1 : kbuf0;
    unsigned short* kn_ = (it & 1) ? kbuf0 : kbuf1;
    __asm__ volatile("s_waitcnt vmcnt(0)" ::: "memory");
    __asm__ volatile("s_barrier" ::: "memory");
    // issue V[t] and K[t+1]
#pragma unroll
    for (int i = 0; i < 4; ++i) {
      int row = wid * 32 + i * 8 + vri;
      async_cp16(vp + (long)row * TLEN + kb + (vrg ^ (row & 7)) * 8,
                 sV + (wid * 32 + i * 8) * 64);
    }
    if (it + 1 < nk) {
      const unsigned short* kp1 = kp + (long)(kb + 64) * HDIM;
#pragma unroll
      for (int i = 0; i < 4; ++i) {
        int row = wid * 16 + i * 4 + kri;
        async_cp16(kp1 + (long)row * HDIM + (krg ^ (row & 7)) * 8,
                   kn_ + (wid * 16 + i * 4) * 128);
      }
    }
    // QK^T: S[16x64] per wave
    f32x4 s[4];
#pragma unroll
    for (int ni = 0; ni < 4; ++ni) s[ni] = (f32x4){0.f, 0.f, 0.f, 0.f};
    __builtin_amdgcn_s_setprio(1);
#pragma unroll
    for (int c = 0; c < 4; ++c) {
      bf16x8 bk[4];
#pragma unroll
      for (int ni = 0; ni < 4; ++ni) {
        int row = ni * 16 + lm;
        int g = (c * 4 + lq) ^ (row & 7);
        bk[ni] = *(const bf16x8*)(&kc_[row * 128 + g * 8]);
      }
#pragma unroll
      for (int ni = 0; ni < 4; ++ni)
        s[ni] = __builtin_amdgcn_mfma_f32_16x16x32_bf16(qf[c], bk[ni], s[ni], 0, 0, 0);
    }
    __builtin_amdgcn_s_setprio(0);
    // online softmax with defer-max (rows lq*4+r, cols kb+ni*16+lm)
    const bool diag = (it == nk - 1);
    float v[4][4], pmax[4];
#pragma unroll
    for (int r = 0; r < 4; ++r) {
      int qrow = q0 + wid * 16 + lq * 4 + r;
      float m = -3.0e38f;
#pragma unroll
      for (int ni = 0; ni < 4; ++ni) {
        float t = s[ni][r] * sl;
        if (diag && (kb + ni * 16 + lm > qrow)) t = -3.0e38f;
        v[r][ni] = t;
        m = fmaxf(m, t);
      }
      pmax[r] = m;
    }
    bool need = (pmax[0] > mr[0] + 8.f) | (pmax[1] > mr[1] + 8.f) |
                (pmax[2] > mr[2] + 8.f) | (pmax[3] > mr[3] + 8.f);
    if (__any(need)) {
#pragma unroll
      for (int r = 0; r < 4; ++r) {
        float m = pmax[r];
#pragma unroll
        for (int off = 8; off >= 1; off >>= 1) m = fmaxf(m, __shfl_xor(m, off));
        float mn = fmaxf(mr[r], m);
        float a = exp2f(mr[r] - mn);
        mr[r] = mn;
        lr[r] *= a;
#pragma unroll
        for (int c = 0; c < 8; ++c) oacc[c][r] *= a;
      }
    }
    float p[4][4];
#pragma unroll
    for (int r = 0; r < 4; ++r) {
      float rs = 0.f;
#pragma unroll
      for (int ni = 0; ni < 4; ++ni) {
        p[r][ni] = exp2f(v[r][ni] - mr[r]);
        rs += p[r][ni];
      }
      lr[r] += rs;  // per-lane partial; reduced once at epilogue
    }
    // V[t] landed (K[t+1] still in flight); barrier closes QK reads of kc_
    if (it + 1 < nk) {
      __asm__ volatile("s_waitcnt vmcnt(4)" ::: "memory");
    } else {
      __asm__ volatile("s_waitcnt vmcnt(0)" ::: "memory");
    }
    __asm__ volatile("s_barrier" ::: "memory");
    // P overlay into consumed K buffer (per-wave 16x64 region)
    unsigned short* pw = kc_ + wid * 1024;
#pragma unroll
    for (int r = 0; r < 4; ++r) {
      int prow = lq * 4 + r;
#pragma unroll
      for (int ni = 0; ni < 4; ++ni)
        pw[prow * 64 + ((ni * 16 + lm) ^ ((prow & 7) << 3))] = f32_bf16(p[r][ni]);
    }
    __asm__ volatile("s_waitcnt lgkmcnt(0)" ::: "memory");  // own-wave P visible
    __builtin_amdgcn_sched_barrier(0);
    // PV: O[16x128] += P[16x64] * V[64x128]
    __builtin_amdgcn_s_setprio(1);
#pragma unroll
    for (int kc = 0; kc < 2; ++kc) {
      bf16x8 pf = *(const bf16x8*)(&pw[lm * 64 + ((kc * 32 + lq * 8) ^ ((lm & 7) << 3))]);
#pragma unroll
      for (int c = 0; c < 8; ++c) {
        int row = c * 16 + lm;
        int g = (kc * 4 + lq) ^ (row & 7);
        bf16x8 vf = *(const bf16x8*)(&sV[row * 64 + g * 8]);
        oacc[c] = __builtin_amdgcn_mfma_f32_16x16x32_bf16(pf, vf, oacc[c], 0, 0, 0);
      }
    }
    __builtin_amdgcn_s_setprio(0);
  }
  // epilogue: reduce lr, LDS transpose, coalesced float4 stores
  __syncthreads();
#pragma unroll
  for (int r = 0; r < 4; ++r) {
#pragma unroll
    for (int off = 8; off >= 1; off >>= 1) lr[r] += __shfl_xor(lr[r], off);
  }
  float inv[4];
#pragma unroll
  for (int r = 0; r < 4; ++r) inv[r] = 1.f / lr[r];
  float* sO = (float*)smem;  // 64 x 132 f32 = 33792 B (fits in 48K)
#pragma unroll
  for (int c = 0; c < 8; ++c)
#pragma unroll
    for (int r = 0; r < 4; ++r)
      sO[(wid * 16 + lq * 4 + r) * 132 + c * 16 + lm] = oacc[c][r] * inv[r];
  __syncthreads();
  float* ob = Ob + ((long)b * TLEN + q0) * DDIM + (long)h * HDIM;
#pragma unroll
  for (int i = 0; i < 8; ++i) {
    int idx = i * 256 + tid;
    int row = idx >> 5, c4 = (idx & 31) * 4;
    *(float4*)(ob + (long)row * DDIM + c4) = *(const float4*)(&sO[row * 132 + c4]);
  }
}

// ---------------- launch ----------------
extern "C" void kernel_launch(void* const* d_in, const int* in_sizes, int n_in,
                              void* d_out, int out_size, void* d_ws, size_t ws_size,
                              hipStream_t stream) {
  const float* x   = (const float*)d_in[0];
  const float* Wq  = (const float*)d_in[1];
  const float* bq  = (const float*)d_in[2];
  const float* Wk  = (const float*)d_in[3];
  const float* bk  = (const float*)d_in[4];
  const float* Wv  = (const float*)d_in[5];
  const float* bv  = (const float*)d_in[6];
  const float* W1  = (const float*)d_in[7];
  const float* b1  = (const float*)d_in[8];
  const float* W2  = (const float*)d_in[9];
  const float* b2  = (const float*)d_in[10];
  const float* g1  = (const float*)d_in[11];
  const float* be1 = (const float*)d_in[12];
  const float* g2  = (const float*)d_in[13];
  const float* be2 = (const float*)d_in[14];
  float* out = (float*)d_out;
  char* ws = (char*)d_ws;
  // ws layout (152 MiB): [0,24M) wtqkv | [24M,56M) qb->ff1buf | [56M,88M) kbuf->wt1
  //                      | [88M,120M) vtb->wt2 | [120M,152M) hbf
  unsigned short* wtqkv  = (unsigned short*)(ws + 0L);
  unsigned short* qb     = (unsigned short*)(ws + 25165824L);
  unsigned short* kbuf   = (unsigned short*)(ws + 58720256L);
  unsigned short* vtb    = (unsigned short*)(ws + 92274688L);
  unsigned short* hbf    = (unsigned short*)(ws + 125829120L);
  unsigned short* ff1buf = qb;
  unsigned short* wt1    = kbuf;
  unsigned short* wt2    = vtb;

  dim3 blk(256);
  transpose_bf16_kernel<<<dim3(4, 64, 16), blk, 0, stream>>>(Wq, wtqkv, 2048, 128, 2048L * 128, 2048L * 128);
  transpose_bf16_kernel<<<dim3(4, 64, 16), blk, 0, stream>>>(Wk, wtqkv + 2048L * 2048, 2048, 128, 2048L * 128, 2048L * 128);
  transpose_bf16_kernel<<<dim3(4, 64, 16), blk, 0, stream>>>(Wv, wtqkv + 2L * 2048 * 2048, 2048, 128, 2048L * 128, 2048L * 128);

  ln_kernel<<<dim3(8192), blk, 0, stream>>>(x, g1, be1, hbf);
  gemm_qkv_kernel<<<dim3(64, 16, 3), blk, 0, stream>>>(hbf, wtqkv, qb, kbuf, vtb, bq, bk, bv);
  attn_kernel<<<dim3(2048), blk, 0, stream>>>(qb, kbuf, vtb, out);

  transpose_bf16_kernel<<<dim3(256, 64, 1), blk, 0, stream>>>(W1, wt1, 2048, 8192, 0, 0);
  transpose_bf16_kernel<<<dim3(64, 256, 1), blk, 0, stream>>>(W2, wt2, 8192, 2048, 0, 0);

  resid_ln_kernel<<<dim3(8192), blk, 0, stream>>>(x, out, g2, be2, hbf);

  // FFN, N-sliced: slice s covers FF1 cols [s*2048, (s+1)*2048).
  // ffn0: ff1_slice = relu(hbf @ W1[:,slice] + b1[slice])   (M=8192, N=2048, K=2048)
  // ffn1: out += ff1_slice @ W2[slice,:] (+b2 on s=0)        (M=8192, N=2048, K=2048)
  for (int s = 0; s < 4; ++s) {
    gemm_ffn_kernel<0><<<dim3(64, 16), blk, 0, stream>>>(
        hbf, wt1 + (long)s * 2048 * 2048, ff1buf, b1 + s * 2048,
        2048, 2048, 2048, 2048);
    if (s == 0) {
      gemm_ffn_kernel<1><<<dim3(64, 16), blk, 0, stream>>>(
          ff1buf, wt2 + (long)s * 2048, out, b2, 2048, 2048, 8192, 2048);
    } else {
      gemm_ffn_kernel<2><<<dim3(64, 16), blk, 0, stream>>>(
          ff1buf, wt2 + (long)s * 2048, out, b2, 2048, 2048, 8192, 2048);
    }
  }
}

// Round 6
// 1463.417 us; speedup vs baseline: 1.4222x; 1.0436x over previous
//
#include <hip/hip_runtime.h>
#include <stdint.h>

#define TLEN 2048
#define DDIM 2048
#define NHEAD 16
#define HDIM 128
#define BSZ 4

typedef short bf16x8 __attribute__((ext_vector_type(8)));
typedef float f32x4 __attribute__((ext_vector_type(4)));

__device__ __forceinline__ unsigned short f32_bf16(float f) {
  union { float f; unsigned int u; } v; v.f = f;
  unsigned int u = v.u;
  unsigned int r = (u + 0x7fffu + ((u >> 16) & 1u)) >> 16;
  return (unsigned short)r;
}

// async 16B global->LDS (dest = wave-uniform base + lane*16)
__device__ __forceinline__ void async_cp16(const void* g, void* l) {
  __builtin_amdgcn_global_load_lds(
      (const __attribute__((address_space(1))) unsigned int*)g,
      (__attribute__((address_space(3))) unsigned int*)l, 16, 0, 0);
}

// ---------------- weight transpose + f32->bf16 convert ----------------
__global__ __launch_bounds__(256) void transpose_bf16_kernel(
    const float* __restrict__ in, unsigned short* __restrict__ out,
    int R, int C, long in_z, long out_z) {
  __shared__ float tile[32][33];
  in += (long)blockIdx.z * in_z;
  out += (long)blockIdx.z * out_z;
  int c0 = blockIdx.x * 32, r0 = blockIdx.y * 32;
  int cr = threadIdx.x & 31, rr = threadIdx.x >> 5;
#pragma unroll
  for (int i = 0; i < 4; ++i)
    tile[rr + i * 8][cr] = in[(long)(r0 + rr + i * 8) * C + c0 + cr];
  __syncthreads();
#pragma unroll
  for (int i = 0; i < 4; ++i)
    out[(long)(c0 + rr + i * 8) * R + r0 + cr] = f32_bf16(tile[cr][rr + i * 8]);
}

// ---------------- block reduction helper (sum, sumsq) ----------------
__device__ __forceinline__ void block_reduce2(float& s, float& q) {
#pragma unroll
  for (int off = 32; off >= 1; off >>= 1) {
    s += __shfl_xor(s, off);
    q += __shfl_xor(q, off);
  }
  __shared__ float rs[4], rq[4];
  int lane = threadIdx.x & 63, wid = threadIdx.x >> 6;
  if (lane == 0) { rs[wid] = s; rq[wid] = q; }
  __syncthreads();
  s = rs[0] + rs[1] + rs[2] + rs[3];
  q = rq[0] + rq[1] + rq[2] + rq[3];
}

// ---------------- LN1: x -> bf16 normalized ----------------
__global__ __launch_bounds__(256) void ln_kernel(
    const float* __restrict__ x, const float* __restrict__ g,
    const float* __restrict__ be, unsigned short* __restrict__ hb) {
  int row = blockIdx.x, tid = threadIdx.x;
  const float* xr = x + (long)row * DDIM;
  float4 v0 = *(const float4*)(xr + tid * 4);
  float4 v1 = *(const float4*)(xr + 1024 + tid * 4);
  float s = v0.x + v0.y + v0.z + v0.w + v1.x + v1.y + v1.z + v1.w;
  float q = v0.x * v0.x + v0.y * v0.y + v0.z * v0.z + v0.w * v0.w +
            v1.x * v1.x + v1.y * v1.y + v1.z * v1.z + v1.w * v1.w;
  block_reduce2(s, q);
  float mu = s * (1.0f / DDIM);
  float var = q * (1.0f / DDIM) - mu * mu;
  float rstd = rsqrtf(var + 1e-5f);
  float4 g0 = *(const float4*)(g + tid * 4);
  float4 g1v = *(const float4*)(g + 1024 + tid * 4);
  float4 b0 = *(const float4*)(be + tid * 4);
  float4 b1v = *(const float4*)(be + 1024 + tid * 4);
  ushort4 o0, o1;
  o0.x = f32_bf16((v0.x - mu) * rstd * g0.x + b0.x);
  o0.y = f32_bf16((v0.y - mu) * rstd * g0.y + b0.y);
  o0.z = f32_bf16((v0.z - mu) * rstd * g0.z + b0.z);
  o0.w = f32_bf16((v0.w - mu) * rstd * g0.w + b0.w);
  o1.x = f32_bf16((v1.x - mu) * rstd * g1v.x + b1v.x);
  o1.y = f32_bf16((v1.y - mu) * rstd * g1v.y + b1v.y);
  o1.z = f32_bf16((v1.z - mu) * rstd * g1v.z + b1v.z);
  o1.w = f32_bf16((v1.w - mu) * rstd * g1v.w + b1v.w);
  *(ushort4*)(hb + (long)row * DDIM + tid * 4) = o0;
  *(ushort4*)(hb + (long)row * DDIM + 1024 + tid * 4) = o1;
}

// ---------------- residual + LN2 (IN PLACE on xa==d_out) ----------------
__global__ __launch_bounds__(256) void resid_ln_kernel(
    const float* __restrict__ x, float* xa,
    const float* __restrict__ g, const float* __restrict__ be,
    unsigned short* __restrict__ hb) {
  int row = blockIdx.x, tid = threadIdx.x;
  const float* xr = x + (long)row * DDIM;
  float* ar = xa + (long)row * DDIM;
  float4 v0 = *(const float4*)(xr + tid * 4);
  float4 a0 = *(const float4*)(ar + tid * 4);
  float4 v1 = *(const float4*)(xr + 1024 + tid * 4);
  float4 a1 = *(const float4*)(ar + 1024 + tid * 4);
  v0.x += a0.x; v0.y += a0.y; v0.z += a0.z; v0.w += a0.w;
  v1.x += a1.x; v1.y += a1.y; v1.z += a1.z; v1.w += a1.w;
  *(float4*)(ar + tid * 4) = v0;
  *(float4*)(ar + 1024 + tid * 4) = v1;
  float s = v0.x + v0.y + v0.z + v0.w + v1.x + v1.y + v1.z + v1.w;
  float q = v0.x * v0.x + v0.y * v0.y + v0.z * v0.z + v0.w * v0.w +
            v1.x * v1.x + v1.y * v1.y + v1.z * v1.z + v1.w * v1.w;
  block_reduce2(s, q);
  float mu = s * (1.0f / DDIM);
  float var = q * (1.0f / DDIM) - mu * mu;
  float rstd = rsqrtf(var + 1e-5f);
  float4 g0 = *(const float4*)(g + tid * 4);
  float4 g1v = *(const float4*)(g + 1024 + tid * 4);
  float4 b0 = *(const float4*)(be + tid * 4);
  float4 b1v = *(const float4*)(be + 1024 + tid * 4);
  ushort4 o0, o1;
  o0.x = f32_bf16((v0.x - mu) * rstd * g0.x + b0.x);
  o0.y = f32_bf16((v0.y - mu) * rstd * g0.y + b0.y);
  o0.z = f32_bf16((v0.z - mu) * rstd * g0.z + b0.z);
  o0.w = f32_bf16((v0.w - mu) * rstd * g0.w + b0.w);
  o1.x = f32_bf16((v1.x - mu) * rstd * g1v.x + b1v.x);
  o1.y = f32_bf16((v1.y - mu) * rstd * g1v.y + b1v.y);
  o1.z = f32_bf16((v1.z - mu) * rstd * g1v.z + b1v.z);
  o1.w = f32_bf16((v1.w - mu) * rstd * g1v.w + b1v.w);
  *(ushort4*)(hb + (long)row * DDIM + tid * 4) = o0;
  *(ushort4*)(hb + (long)row * DDIM + 1024 + tid * 4) = o1;
}

// ---------------- MFMA GEMM core v4: async double-buffered pipeline ----------------
// attn-v6 pattern applied to GEMM: sA/sB double-buffered (64KB LDS), ONE raw
// s_barrier per K-tile, own-wave vmcnt(0) BEFORE the barrier (=> cross-wave load
// visibility), next tile's global_load_lds issued right after the barrier so HBM/L2
// latency hides under the current tile's ds_read+MFMA. No __syncthreads in the loop
// (it would drain the in-flight prefetch).
__device__ __forceinline__ void gemm_core(const unsigned short* __restrict__ A,
                                          const unsigned short* __restrict__ Bt,
                                          int K, int lda, int ldb, int m0, int n0,
                                          f32x4 acc[4][4]) {
  __shared__ unsigned short sA[2][128 * 64];
  __shared__ unsigned short sB[2][128 * 64];
  const int tid = threadIdx.x;
  const int lane = tid & 63, wid = tid >> 6;
  const int wm = (wid & 1) * 64, wn = (wid >> 1) * 64;
  const int lm = lane & 15, lq = lane >> 4;
#pragma unroll
  for (int mi = 0; mi < 4; ++mi)
#pragma unroll
    for (int ni = 0; ni < 4; ++ni)
      acc[mi][ni] = (f32x4){0.f, 0.f, 0.f, 0.f};
  const int rbase = wid * 32;
  const int ri = lane >> 3;
  const int kgl = lane & 7;
  const int nk = K >> 6;
  const unsigned short* Abase = A + (long)m0 * lda;
  const unsigned short* Bbase = Bt + (long)n0 * ldb;
  // prologue: stage tile 0 into buffer 0
#pragma unroll
  for (int ins = 0; ins < 4; ++ins) {
    int row = rbase + ins * 8 + ri;
    int kg = kgl ^ (row & 7);
    async_cp16(Abase + (long)row * lda + kg * 8, &sA[0][(rbase + ins * 8) * 64]);
    async_cp16(Bbase + (long)row * ldb + kg * 8, &sB[0][(rbase + ins * 8) * 64]);
  }
  for (int kt = 0; kt < nk; ++kt) {
    const int cur = kt & 1;
    // own loads(t) landed; barrier => all waves' loads(t) landed AND all waves
    // finished reading buffer cur^1 (iter t-1 compute) so it can be restaged.
    __asm__ volatile("s_waitcnt vmcnt(0)" ::: "memory");
    __asm__ volatile("s_barrier" ::: "memory");
    if (kt + 1 < nk) {
      const unsigned short* Ak = Abase + (long)(kt + 1) * 64;
      const unsigned short* Bk = Bbase + (long)(kt + 1) * 64;
#pragma unroll
      for (int ins = 0; ins < 4; ++ins) {
        int row = rbase + ins * 8 + ri;
        int kg = kgl ^ (row & 7);
        async_cp16(Ak + (long)row * lda + kg * 8, &sA[cur ^ 1][(rbase + ins * 8) * 64]);
        async_cp16(Bk + (long)row * ldb + kg * 8, &sB[cur ^ 1][(rbase + ins * 8) * 64]);
      }
    }
    __builtin_amdgcn_s_setprio(1);
#pragma unroll
    for (int kc = 0; kc < 2; ++kc) {
      bf16x8 af[4], bfr[4];
#pragma unroll
      for (int mi = 0; mi < 4; ++mi) {
        int row = wm + mi * 16 + lm;
        int kg = (kc * 4 + lq) ^ (row & 7);
        af[mi] = *(const bf16x8*)(&sA[cur][row * 64 + kg * 8]);
      }
#pragma unroll
      for (int ni = 0; ni < 4; ++ni) {
        int row = wn + ni * 16 + lm;
        int kg = (kc * 4 + lq) ^ (row & 7);
        bfr[ni] = *(const bf16x8*)(&sB[cur][row * 64 + kg * 8]);
      }
#pragma unroll
      for (int mi = 0; mi < 4; ++mi)
#pragma unroll
        for (int ni = 0; ni < 4; ++ni)
          acc[mi][ni] = __builtin_amdgcn_mfma_f32_16x16x32_bf16(af[mi], bfr[ni], acc[mi][ni], 0, 0, 0);
    }
    __builtin_amdgcn_s_setprio(0);
  }
}

// ---------------- QKV projection GEMM (z: 0=Q,1=K,2=V-transposed) ----------------
__global__ __launch_bounds__(256) void gemm_qkv_kernel(
    const unsigned short* __restrict__ A, const unsigned short* __restrict__ WT,
    unsigned short* __restrict__ Qb, unsigned short* __restrict__ Kb,
    unsigned short* __restrict__ VTb,
    const float* __restrict__ bq, const float* __restrict__ bk,
    const float* __restrict__ bv) {
  int m0 = blockIdx.x * 128, n0 = blockIdx.y * 128;
  int z = blockIdx.z;
  const unsigned short* Bt = WT + (long)z * DDIM * DDIM;
  f32x4 acc[4][4];
  gemm_core(A, Bt, DDIM, DDIM, DDIM, m0, n0, acc);
  const float* bias = (z == 0) ? bq : (z == 1) ? bk : bv;
  int lane = threadIdx.x & 63, wid = threadIdx.x >> 6;
  int wm = (wid & 1) * 64, wn = (wid >> 1) * 64, lm = lane & 15, lq = lane >> 4;
  int h = n0 >> 7;
#pragma unroll
  for (int mi = 0; mi < 4; ++mi) {
    int rowb = m0 + wm + mi * 16 + lq * 4;
    int b = rowb >> 11, t0 = rowb & (TLEN - 1);
#pragma unroll
    for (int ni = 0; ni < 4; ++ni) {
      int col = n0 + wn + ni * 16 + lm;
      int e = col & (HDIM - 1);
      float bsv = bias[col];
      if (z < 2) {
        unsigned short* o = (z == 0) ? Qb : Kb;
        long base = ((long)(b * NHEAD + h) * TLEN + t0) * HDIM + e;
#pragma unroll
        for (int r = 0; r < 4; ++r)
          o[base + (long)r * HDIM] = f32_bf16(acc[mi][ni][r] + bsv);
      } else {
        long base = ((long)(b * NHEAD + h) * HDIM + e) * TLEN + t0;
        ushort4 pk;
        pk.x = f32_bf16(acc[mi][ni][0] + bsv);
        pk.y = f32_bf16(acc[mi][ni][1] + bsv);
        pk.z = f32_bf16(acc[mi][ni][2] + bsv);
        pk.w = f32_bf16(acc[mi][ni][3] + bsv);
        *(ushort4*)(VTb + base) = pk;
      }
    }
  }
}

// ---------------- FFN GEMMs (N-sliced, all dispatches 1024 blocks) ----------------
// MODE 0: +bias, ReLU -> bf16 (ff1 slice). MODE 1: +bias + resid accumulate -> f32.
// MODE 2: resid accumulate only -> f32 (slices 1..3).
template <int MODE>
__global__ __launch_bounds__(256) void gemm_ffn_kernel(
    const unsigned short* __restrict__ A, const unsigned short* __restrict__ Bt,
    void* __restrict__ outv, const float* __restrict__ bias,
    int K, int lda, int ldb, int N) {
  int m0 = blockIdx.x * 128, n0 = blockIdx.y * 128;
  f32x4 acc[4][4];
  gemm_core(A, Bt, K, lda, ldb, m0, n0, acc);
  int lane = threadIdx.x & 63, wid = threadIdx.x >> 6;
  int wm = (wid & 1) * 64, wn = (wid >> 1) * 64, lm = lane & 15, lq = lane >> 4;
#pragma unroll
  for (int mi = 0; mi < 4; ++mi) {
    int rowb = m0 + wm + mi * 16 + lq * 4;
#pragma unroll
    for (int ni = 0; ni < 4; ++ni) {
      int col = n0 + wn + ni * 16 + lm;
      float bsv = (MODE == 2) ? 0.f : bias[col];
#pragma unroll
      for (int r = 0; r < 4; ++r) {
        long idx = (long)(rowb + r) * N + col;
        float v = acc[mi][ni][r] + bsv;
        if (MODE == 0) {
          ((unsigned short*)outv)[idx] = f32_bf16(v > 0.f ? v : 0.f);
        } else {
          float* o = (float*)outv;
          o[idx] = o[idx] + v;
        }
      }
    }
  }
}

// ---------------- Flash attention v6: async pipeline + defer-max ----------------
// K double-buffered (2x16KB), V single-buffered (16KB), P overlays consumed K buffer.
// Raw s_barrier + counted vmcnt keep K(t+1)/V(t) loads in flight across barriers.
// Defer-max (T13, THR=8 in log2 domain): skip shuffle-max + O/l rescale unless some
// lane's local tile max exceeds mr+8; exact softmax recovered by final 1/l.
__global__ __launch_bounds__(256, 3) void attn_kernel(
    const unsigned short* __restrict__ Qb, const unsigned short* __restrict__ Kb,
    const unsigned short* __restrict__ VTb, float* __restrict__ Ob) {
  __shared__ __align__(16) char smem[49152];
  unsigned short* kbuf0 = (unsigned short*)smem;            // 64x128 bf16
  unsigned short* kbuf1 = (unsigned short*)(smem + 16384);  // 64x128 bf16
  unsigned short* sV = (unsigned short*)(smem + 32768);     // 128x64 bf16
  const int tid = threadIdx.x, lane = tid & 63, wid = tid >> 6;
  const int lm = lane & 15, lq = lane >> 4;
  int flat = blockIdx.x;
  int swz = (flat & 7) * 256 + (flat >> 3);
  int m5 = swz & 31;
  int bxx = (m5 & 1) ? (m5 >> 1) : (31 - (m5 >> 1));
  int h = (swz >> 5) & 15;
  int b = swz >> 9;
  const int q0 = bxx * 64;
  const long bh = (long)(b * NHEAD + h);
  const unsigned short* qp = Qb + (bh * TLEN + q0 + wid * 16) * HDIM;
  const unsigned short* kp = Kb + bh * TLEN * HDIM;
  const unsigned short* vp = VTb + bh * HDIM * TLEN;
  bf16x8 qf[4];
#pragma unroll
  for (int c = 0; c < 4; ++c)
    qf[c] = *(const bf16x8*)(qp + (long)lm * HDIM + c * 32 + lq * 8);
  f32x4 oacc[8];
#pragma unroll
  for (int c = 0; c < 8; ++c) oacc[c] = (f32x4){0.f, 0.f, 0.f, 0.f};
  float mr[4], lr[4];
#pragma unroll
  for (int r = 0; r < 4; ++r) { mr[r] = -3.0e38f; lr[r] = 0.f; }
  const float sl = 0.08838834764831845f * 1.4426950408889634f;  // scale * log2(e)
  const int nk = bxx + 1;
  const int kri = lane >> 4, krg = lane & 15;   // K stage: 4 rows x 16 granules
  const int vri = lane >> 3, vrg = lane & 7;    // V stage: 8 rows x 8 granules
  // prologue: issue K[0]
#pragma unroll
  for (int i = 0; i < 4; ++i) {
    int row = wid * 16 + i * 4 + kri;
    async_cp16(kp + (long)row * HDIM + (krg ^ (row & 7)) * 8,
               kbuf0 + (wid * 16 + i * 4) * 128);
  }
  for (int it = 0; it < nk; ++it) {
    const int kb = it * 64;
    unsigned short* kc_ = (it & 1) ? kbuf1 : kbuf0;
    unsigned short* kn_ = (it & 1) ? kbuf0 : kbuf1;
    __asm__ volatile("s_waitcnt vmcnt(0)" ::: "memory");
    __asm__ volatile("s_barrier" ::: "memory");
    // issue V[t] and K[t+1]
#pragma unroll
    for (int i = 0; i < 4; ++i) {
      int row = wid * 32 + i * 8 + vri;
      async_cp16(vp + (long)row * TLEN + kb + (vrg ^ (row & 7)) * 8,
                 sV + (wid * 32 + i * 8) * 64);
    }
    if (it + 1 < nk) {
      const unsigned short* kp1 = kp + (long)(kb + 64) * HDIM;
#pragma unroll
      for (int i = 0; i < 4; ++i) {
        int row = wid * 16 + i * 4 + kri;
        async_cp16(kp1 + (long)row * HDIM + (krg ^ (row & 7)) * 8,
                   kn_ + (wid * 16 + i * 4) * 128);
      }
    }
    // QK^T: S[16x64] per wave
    f32x4 s[4];
#pragma unroll
    for (int ni = 0; ni < 4; ++ni) s[ni] = (f32x4){0.f, 0.f, 0.f, 0.f};
    __builtin_amdgcn_s_setprio(1);
#pragma unroll
    for (int c = 0; c < 4; ++c) {
      bf16x8 bk[4];
#pragma unroll
      for (int ni = 0; ni < 4; ++ni) {
        int row = ni * 16 + lm;
        int g = (c * 4 + lq) ^ (row & 7);
        bk[ni] = *(const bf16x8*)(&kc_[row * 128 + g * 8]);
      }
#pragma unroll
      for (int ni = 0; ni < 4; ++ni)
        s[ni] = __builtin_amdgcn_mfma_f32_16x16x32_bf16(qf[c], bk[ni], s[ni], 0, 0, 0);
    }
    __builtin_amdgcn_s_setprio(0);
    // online softmax with defer-max (rows lq*4+r, cols kb+ni*16+lm)
    const bool diag = (it == nk - 1);
    float v[4][4], pmax[4];
#pragma unroll
    for (int r = 0; r < 4; ++r) {
      int qrow = q0 + wid * 16 + lq * 4 + r;
      float m = -3.0e38f;
#pragma unroll
      for (int ni = 0; ni < 4; ++ni) {
        float t = s[ni][r] * sl;
        if (diag && (kb + ni * 16 + lm > qrow)) t = -3.0e38f;
        v[r][ni] = t;
        m = fmaxf(m, t);
      }
      pmax[r] = m;
    }
    bool need = (pmax[0] > mr[0] + 8.f) | (pmax[1] > mr[1] + 8.f) |
                (pmax[2] > mr[2] + 8.f) | (pmax[3] > mr[3] + 8.f);
    if (__any(need)) {
#pragma unroll
      for (int r = 0; r < 4; ++r) {
        float m = pmax[r];
#pragma unroll
        for (int off = 8; off >= 1; off >>= 1) m = fmaxf(m, __shfl_xor(m, off));
        float mn = fmaxf(mr[r], m);
        float a = exp2f(mr[r] - mn);
        mr[r] = mn;
        lr[r] *= a;
#pragma unroll
        for (int c = 0; c < 8; ++c) oacc[c][r] *= a;
      }
    }
    float p[4][4];
#pragma unroll
    for (int r = 0; r < 4; ++r) {
      float rs = 0.f;
#pragma unroll
      for (int ni = 0; ni < 4; ++ni) {
        p[r][ni] = exp2f(v[r][ni] - mr[r]);
        rs += p[r][ni];
      }
      lr[r] += rs;  // per-lane partial; reduced once at epilogue
    }
    // V[t] landed (K[t+1] still in flight); barrier closes QK reads of kc_
    if (it + 1 < nk) {
      __asm__ volatile("s_waitcnt vmcnt(4)" ::: "memory");
    } else {
      __asm__ volatile("s_waitcnt vmcnt(0)" ::: "memory");
    }
    __asm__ volatile("s_barrier" ::: "memory");
    // P overlay into consumed K buffer (per-wave 16x64 region)
    unsigned short* pw = kc_ + wid * 1024;
#pragma unroll
    for (int r = 0; r < 4; ++r) {
      int prow = lq * 4 + r;
#pragma unroll
      for (int ni = 0; ni < 4; ++ni)
        pw[prow * 64 + ((ni * 16 + lm) ^ ((prow & 7) << 3))] = f32_bf16(p[r][ni]);
    }
    __asm__ volatile("s_waitcnt lgkmcnt(0)" ::: "memory");  // own-wave P visible
    __builtin_amdgcn_sched_barrier(0);
    // PV: O[16x128] += P[16x64] * V[64x128]
    __builtin_amdgcn_s_setprio(1);
#pragma unroll
    for (int kc = 0; kc < 2; ++kc) {
      bf16x8 pf = *(const bf16x8*)(&pw[lm * 64 + ((kc * 32 + lq * 8) ^ ((lm & 7) << 3))]);
#pragma unroll
      for (int c = 0; c < 8; ++c) {
        int row = c * 16 + lm;
        int g = (kc * 4 + lq) ^ (row & 7);
        bf16x8 vf = *(const bf16x8*)(&sV[row * 64 + g * 8]);
        oacc[c] = __builtin_amdgcn_mfma_f32_16x16x32_bf16(pf, vf, oacc[c], 0, 0, 0);
      }
    }
    __builtin_amdgcn_s_setprio(0);
  }
  // epilogue: reduce lr, LDS transpose, coalesced float4 stores
  __syncthreads();
#pragma unroll
  for (int r = 0; r < 4; ++r) {
#pragma unroll
    for (int off = 8; off >= 1; off >>= 1) lr[r] += __shfl_xor(lr[r], off);
  }
  float inv[4];
#pragma unroll
  for (int r = 0; r < 4; ++r) inv[r] = 1.f / lr[r];
  float* sO = (float*)smem;  // 64 x 132 f32 = 33792 B (fits in 48K)
#pragma unroll
  for (int c = 0; c < 8; ++c)
#pragma unroll
    for (int r = 0; r < 4; ++r)
      sO[(wid * 16 + lq * 4 + r) * 132 + c * 16 + lm] = oacc[c][r] * inv[r];
  __syncthreads();
  float* ob = Ob + ((long)b * TLEN + q0) * DDIM + (long)h * HDIM;
#pragma unroll
  for (int i = 0; i < 8; ++i) {
    int idx = i * 256 + tid;
    int row = idx >> 5, c4 = (idx & 31) * 4;
    *(float4*)(ob + (long)row * DDIM + c4) = *(const float4*)(&sO[row * 132 + c4]);
  }
}

// ---------------- launch ----------------
extern "C" void kernel_launch(void* const* d_in, const int* in_sizes, int n_in,
                              void* d_out, int out_size, void* d_ws, size_t ws_size,
                              hipStream_t stream) {
  const float* x   = (const float*)d_in[0];
  const float* Wq  = (const float*)d_in[1];
  const float* bq  = (const float*)d_in[2];
  const float* Wk  = (const float*)d_in[3];
  const float* bk  = (const float*)d_in[4];
  const float* Wv  = (const float*)d_in[5];
  const float* bv  = (const float*)d_in[6];
  const float* W1  = (const float*)d_in[7];
  const float* b1  = (const float*)d_in[8];
  const float* W2  = (const float*)d_in[9];
  const float* b2  = (const float*)d_in[10];
  const float* g1  = (const float*)d_in[11];
  const float* be1 = (const float*)d_in[12];
  const float* g2  = (const float*)d_in[13];
  const float* be2 = (const float*)d_in[14];
  float* out = (float*)d_out;
  char* ws = (char*)d_ws;
  // ws layout (152 MiB): [0,24M) wtqkv | [24M,56M) qb->ff1buf | [56M,88M) kbuf->wt1
  //                      | [88M,120M) vtb->wt2 | [120M,152M) hbf
  unsigned short* wtqkv  = (unsigned short*)(ws + 0L);
  unsigned short* qb     = (unsigned short*)(ws + 25165824L);
  unsigned short* kbuf   = (unsigned short*)(ws + 58720256L);
  unsigned short* vtb    = (unsigned short*)(ws + 92274688L);
  unsigned short* hbf    = (unsigned short*)(ws + 125829120L);
  unsigned short* ff1buf = qb;
  unsigned short* wt1    = kbuf;
  unsigned short* wt2    = vtb;

  dim3 blk(256);
  transpose_bf16_kernel<<<dim3(4, 64, 16), blk, 0, stream>>>(Wq, wtqkv, 2048, 128, 2048L * 128, 2048L * 128);
  transpose_bf16_kernel<<<dim3(4, 64, 16), blk, 0, stream>>>(Wk, wtqkv + 2048L * 2048, 2048, 128, 2048L * 128, 2048L * 128);
  transpose_bf16_kernel<<<dim3(4, 64, 16), blk, 0, stream>>>(Wv, wtqkv + 2L * 2048 * 2048, 2048, 128, 2048L * 128, 2048L * 128);

  ln_kernel<<<dim3(8192), blk, 0, stream>>>(x, g1, be1, hbf);
  gemm_qkv_kernel<<<dim3(64, 16, 3), blk, 0, stream>>>(hbf, wtqkv, qb, kbuf, vtb, bq, bk, bv);
  attn_kernel<<<dim3(2048), blk, 0, stream>>>(qb, kbuf, vtb, out);

  transpose_bf16_kernel<<<dim3(256, 64, 1), blk, 0, stream>>>(W1, wt1, 2048, 8192, 0, 0);
  transpose_bf16_kernel<<<dim3(64, 256, 1), blk, 0, stream>>>(W2, wt2, 8192, 2048, 0, 0);

  resid_ln_kernel<<<dim3(8192), blk, 0, stream>>>(x, out, g2, be2, hbf);

  // FFN, N-sliced: slice s covers FF1 cols [s*2048, (s+1)*2048).
  // ffn0: ff1_slice = relu(hbf @ W1[:,slice] + b1[slice])   (M=8192, N=2048, K=2048)
  // ffn1: out += ff1_slice @ W2[slice,:] (+b2 on s=0)        (M=8192, N=2048, K=2048)
  for (int s = 0; s < 4; ++s) {
    gemm_ffn_kernel<0><<<dim3(64, 16), blk, 0, stream>>>(
        hbf, wt1 + (long)s * 2048 * 2048, ff1buf, b1 + s * 2048,
        2048, 2048, 2048, 2048);
    if (s == 0) {
      gemm_ffn_kernel<1><<<dim3(64, 16), blk, 0, stream>>>(
          ff1buf, wt2 + (long)s * 2048, out, b2, 2048, 2048, 8192, 2048);
    } else {
      gemm_ffn_kernel<2><<<dim3(64, 16), blk, 0, stream>>>(
          ff1buf, wt2 + (long)s * 2048, out, b2, 2048, 2048, 8192, 2048);
    }
  }
}